// Round 7
// baseline (3089.738 us; speedup 1.0000x reference)
//
#include <hip/hip_runtime.h>

typedef unsigned short u16;
typedef unsigned int u32;
typedef __bf16 bf16_t;
typedef bf16_t bf16x8 __attribute__((ext_vector_type(8)));
typedef float f32x4 __attribute__((ext_vector_type(4)));

#define LDS_PTR(p) ((__attribute__((address_space(3))) unsigned int*)(p))
#define GLB_PTR(p) ((const __attribute__((address_space(1))) unsigned int*)(p))

#define BSH 9                 // bucket shift: 512 nodes per bucket
#define BCAP 32768            // pair capacity per bucket

static __device__ __forceinline__ float bf2f(u16 h) {
  u32 u = ((u32)h) << 16;
  return __builtin_bit_cast(float, u);
}
static __device__ __forceinline__ u16 f2bf(float f) {
  u32 u = __builtin_bit_cast(u32, f);
  u += 0x7fffu + ((u >> 16) & 1u);
  return (u16)(u >> 16);
}
static __device__ __forceinline__ void accum_d(float* acc, int j, u32 d, float w) {
  float lo = __builtin_bit_cast(float, d << 16);
  float hi = __builtin_bit_cast(float, d & 0xffff0000u);
  acc[j] += w * lo;
  acc[j + 1] += w * hi;
}

// ---------------- detection ----------------
__global__ void detect_edge_kernel(const int* __restrict__ ei, int* __restrict__ flags) {
  __shared__ int nz;
  if (threadIdx.x == 0) nz = 0;
  __syncthreads();
  if (ei[1 + 2 * threadIdx.x] != 0) atomicAdd(&nz, 1);
  __syncthreads();
  if (threadIdx.x == 0) flags[0] = (nz == 0) ? 1 : 0;
}

__global__ void detect_x_kernel(const u16* __restrict__ x, int* __restrict__ flags) {
  __shared__ int cnt;
  if (threadIdx.x == 0) cnt = 0;
  __syncthreads();
  u32 u = x[threadIdx.x];
  u32 e = (u >> 7) & 0xFF;
  if (e >= 0x60 && e <= 0x83) atomicAdd(&cnt, 1);
  __syncthreads();
  if (threadIdx.x == 0) flags[1] = (cnt >= 240) ? 0 : 1;
}

static __device__ __forceinline__ int eidx(const void* ei, size_t i, int m) {
  return m ? (int)((const long long*)ei)[i] : ((const int*)ei)[i];
}

// ---------------- utility ----------------
__global__ void zero_kernel(int* __restrict__ p, int n) {
  int i = blockIdx.x * 256 + threadIdx.x;
  if (i < n) p[i] = 0;
}

__global__ void zero_out_kernel(void* __restrict__ out, int n, const int* __restrict__ flags) {
  int i = blockIdx.x * 256 + threadIdx.x;
  if (i < n) {
    if (flags[1]) ((float*)out)[i] = 0.0f;
    else ((u16*)out)[i] = 0;
  }
}

__global__ void copyvec_kernel(const int4* __restrict__ a, int4* __restrict__ b, int n4) {
  int i = blockIdx.x * 256 + threadIdx.x;
  if (i < n4) b[i] = a[i];
}

__global__ void convert_w_kernel(const void* __restrict__ W, u16* __restrict__ Wt,
                                 int K, int N, const int* __restrict__ flags) {
  int idx = blockIdx.x * 256 + threadIdx.x;
  if (idx < K * N) {
    int k = idx / N, n = idx % N;
    float v = flags[1] ? ((const float*)W)[idx] : bf2f(((const u16*)W)[idx]);
    Wt[n * K + k] = f2bf(v);
  }
}

__global__ void copycols_kernel(const u16* __restrict__ S, u16* __restrict__ H, int c0, int Nn) {
  int idx = blockIdx.x * 256 + threadIdx.x;
  if (idx < Nn * 16) {
    int row = idx >> 4, q = idx & 15;
    ((int4*)(H + (size_t)row * 1024 + c0))[q] = ((const int4*)(S + (size_t)row * 128))[q];
  }
}

// ---------------- bucketed CSR build ----------------
__global__ __launch_bounds__(256) void bin_kernel(const void* __restrict__ ei,
                                                  int* __restrict__ gcur,
                                                  int2* __restrict__ pairs, int E, int Nn,
                                                  const int* __restrict__ flags, int nblk) {
  __shared__ int h[256];
  __shared__ int base[256];
  const int m = flags[0];
  const int nb = (Nn + (1 << BSH) - 1) >> BSH;
  const int per = (E + nblk - 1) / nblk;
  const int e0 = blockIdx.x * per;
  const int e1 = (e0 + per < E) ? e0 + per : E;
  for (int i = threadIdx.x; i < nb; i += 256) h[i] = 0;
  __syncthreads();
  for (int e = e0 + threadIdx.x; e < e1; e += 256) {
    int d = eidx(ei, (size_t)E + e, m);
    if ((u32)d < (u32)Nn) atomicAdd(&h[d >> BSH], 1);
  }
  __syncthreads();
  for (int i = threadIdx.x; i < nb; i += 256) {
    base[i] = atomicAdd(&gcur[i], h[i]);
    h[i] = 0;
  }
  __syncthreads();
  for (int e = e0 + threadIdx.x; e < e1; e += 256) {
    int d = eidx(ei, (size_t)E + e, m);
    if ((u32)d >= (u32)Nn) continue;
    int s = eidx(ei, (size_t)e, m);
    if ((u32)s >= (u32)Nn) s = 0;
    int b = d >> BSH;
    int p = base[b] + atomicAdd(&h[b], 1);
    if (p < BCAP) pairs[(size_t)b * BCAP + p] = make_int2(s, d);
  }
}

__global__ __launch_bounds__(256) void bucket_count_kernel(const int2* __restrict__ pairs,
                                                           const int* __restrict__ gcur,
                                                           int* __restrict__ deg, int Nn) {
  __shared__ int cnt[1 << BSH];
  const int b = blockIdx.x;
  const int n0 = b << BSH;
  for (int j = threadIdx.x; j < (1 << BSH); j += 256) cnt[j] = 0;
  __syncthreads();
  int tot = gcur[b];
  if (tot > BCAP) tot = BCAP;
  for (int i = threadIdx.x; i < tot; i += 256) {
    int2 pr = pairs[(size_t)b * BCAP + i];
    atomicAdd(&cnt[pr.y - n0], 1);
  }
  __syncthreads();
  for (int j = threadIdx.x; j < (1 << BSH); j += 256) {
    int node = n0 + j;
    if (node < Nn) deg[node] = cnt[j];
  }
}

__global__ __launch_bounds__(1024) void scan_kernel(const int* __restrict__ deg,
                                                    int* __restrict__ rowp,
                                                    float* __restrict__ dinv, int Nn) {
  __shared__ int sd[1024];
  int tid = threadIdx.x;
  int carry = 0;
  if (tid == 0) rowp[0] = 0;
  for (int base = 0; base < Nn; base += 4096) {
    int i0 = base + tid * 4;
    int v[4];
    int tot = 0;
#pragma unroll
    for (int j = 0; j < 4; ++j) {
      v[j] = (i0 + j < Nn) ? deg[i0 + j] : 0;
      tot += v[j];
    }
    sd[tid] = tot;
    __syncthreads();
    for (int s = 1; s < 1024; s <<= 1) {
      int t = (tid >= s) ? sd[tid - s] : 0;
      __syncthreads();
      sd[tid] += t;
      __syncthreads();
    }
    int run = carry + sd[tid] - tot;
#pragma unroll
    for (int j = 0; j < 4; ++j) {
      if (i0 + j < Nn) {
        dinv[i0 + j] = rsqrtf((float)(v[j] + 1));  // +1 self loop
        run += v[j];
        rowp[i0 + j + 1] = run;
      }
    }
    carry += sd[1023];
    __syncthreads();
  }
}

__global__ __launch_bounds__(256) void bucket_place_kernel(const int2* __restrict__ pairs,
                                                           const int* __restrict__ gcur,
                                                           const int* __restrict__ rowp,
                                                           int* __restrict__ csr, int Nn) {
  __shared__ int cur[1 << BSH];
  const int b = blockIdx.x;
  const int n0 = b << BSH;
  for (int j = threadIdx.x; j < (1 << BSH); j += 256) {
    int node = n0 + j;
    cur[j] = (node < Nn) ? rowp[node] : 0;
  }
  __syncthreads();
  int tot = gcur[b];
  if (tot > BCAP) tot = BCAP;
  for (int i = threadIdx.x; i < tot; i += 256) {
    int2 pr = pairs[(size_t)b * BCAP + i];
    int p = atomicAdd(&cur[pr.y - n0], 1);
    csr[p] = pr.x;
  }
}

// ---------------- wide pull-SpMM: G = W/8 lanes per node, 16 B per lane per edge ----------------
// Every lane owns 8 columns [l*8, l*8+8) of its node's row. Batch-8 clamped edge loads.
template <int W, bool SRCF>
__global__ __launch_bounds__(256) void spmm_wide_kernel(
    const void* __restrict__ Hb, void* __restrict__ Gb,
    const int* __restrict__ rowp, const int* __restrict__ csr,
    const float* __restrict__ dinv, const u16* __restrict__ bias,
    int relu, int Nn, int src_stride, long long src_coloff,
    int dst_stride, long long dst_coloff, const int* __restrict__ flags) {
  constexpr int G = W / 8;        // lanes per node
  constexpr int NPB = 256 / G;    // nodes per block
  const int l = threadIdx.x & (G - 1);
  const int node = blockIdx.x * NPB + (threadIdx.x / G);
  const bool active = node < Nn;
  const int off = l * 8;
  int sf32 = SRCF ? flags[1] : 0;
  const u16* Hs = (const u16*)Hb;
  const float* Hf = (const float*)Hb;

  int e0 = 0, cnt = 0;
  if (active) {
    e0 = rowp[node];
    cnt = rowp[node + 1] - e0;
  }
  float acc[8];
#pragma unroll
  for (int k = 0; k < 8; ++k) acc[k] = 0.0f;

  if (!(SRCF && sf32)) {
    for (int jb = 0; jb < cnt; jb += 8) {
      int s[8];
      float wv[8];
#pragma unroll
      for (int j = 0; j < 8; ++j) {
        bool val = (jb + j) < cnt;
        s[j] = val ? csr[e0 + jb + j] : node;
        wv[j] = val ? dinv[s[j]] : 0.0f;
      }
      int4 v[8];
#pragma unroll
      for (int j = 0; j < 8; ++j)
        v[j] = *(const int4*)(Hs + (size_t)src_coloff + (size_t)s[j] * src_stride + off);
#pragma unroll
      for (int j = 0; j < 8; ++j) {
        accum_d(acc, 0, (u32)v[j].x, wv[j]);
        accum_d(acc, 2, (u32)v[j].y, wv[j]);
        accum_d(acc, 4, (u32)v[j].z, wv[j]);
        accum_d(acc, 6, (u32)v[j].w, wv[j]);
      }
    }
  } else {
    for (int jb = 0; jb < cnt; jb += 8) {
      int s[8];
      float wv[8];
#pragma unroll
      for (int j = 0; j < 8; ++j) {
        bool val = (jb + j) < cnt;
        s[j] = val ? csr[e0 + jb + j] : node;
        wv[j] = val ? dinv[s[j]] : 0.0f;
      }
      float4 va[8], vb[8];
#pragma unroll
      for (int j = 0; j < 8; ++j) {
        const float* rp = Hf + (size_t)src_coloff + (size_t)s[j] * src_stride + off;
        va[j] = *(const float4*)rp;
        vb[j] = *(const float4*)(rp + 4);
      }
#pragma unroll
      for (int j = 0; j < 8; ++j) {
        acc[0] += wv[j] * va[j].x; acc[1] += wv[j] * va[j].y;
        acc[2] += wv[j] * va[j].z; acc[3] += wv[j] * va[j].w;
        acc[4] += wv[j] * vb[j].x; acc[5] += wv[j] * vb[j].y;
        acc[6] += wv[j] * vb[j].z; acc[7] += wv[j] * vb[j].w;
      }
    }
  }

  if (!active) return;
  const float wi = dinv[node];
  {  // self loop
    if (SRCF && sf32) {
      const float* rp = Hf + (size_t)src_coloff + (size_t)node * src_stride + off;
      float4 a = *(const float4*)rp, b = *(const float4*)(rp + 4);
      acc[0] += wi * a.x; acc[1] += wi * a.y; acc[2] += wi * a.z; acc[3] += wi * a.w;
      acc[4] += wi * b.x; acc[5] += wi * b.y; acc[6] += wi * b.z; acc[7] += wi * b.w;
    } else {
      int4 v = *(const int4*)(Hs + (size_t)src_coloff + (size_t)node * src_stride + off);
      accum_d(acc, 0, (u32)v.x, wi);
      accum_d(acc, 2, (u32)v.y, wi);
      accum_d(acc, 4, (u32)v.z, wi);
      accum_d(acc, 6, (u32)v.w, wi);
    }
  }
  float vals[8];
#pragma unroll
  for (int k = 0; k < 8; ++k) {
    float v = acc[k] * wi;
    if (bias) v += bf2f(bias[off + k]);
    if (relu) v = fmaxf(v, 0.0f);
    vals[k] = v;
  }
  u32 d[4];
#pragma unroll
  for (int k = 0; k < 4; ++k)
    d[k] = (u32)f2bf(vals[2 * k]) | ((u32)f2bf(vals[2 * k + 1]) << 16);
  *(int4*)((u16*)Gb + (size_t)dst_coloff + (size_t)node * dst_stride + off) =
      make_int4((int)d[0], (int)d[1], (int)d[2], (int)d[3]);
}

// ---------------- narrow pull-SpMM (W=6 final layer) ----------------
template <int W, bool DSTF>
__global__ __launch_bounds__(256) void spmm_narrow_kernel(
    const void* __restrict__ Hb, void* __restrict__ Gb,
    const int* __restrict__ rowp, const int* __restrict__ csr,
    const float* __restrict__ dinv, const u16* __restrict__ bias,
    int relu, int Nn, int src_stride, long long src_coloff,
    int dst_stride, long long dst_coloff, const int* __restrict__ flags) {
  constexpr int B = 16;
  const int lane = threadIdx.x & 63;
  const int node = __builtin_amdgcn_readfirstlane(blockIdx.x * 4 + (threadIdx.x >> 6));
  if (node >= Nn) return;
  const bool act = lane < W;
  const int off = lane;
  int of32 = DSTF ? flags[1] : 0;
  const u16* Hs = (const u16*)Hb;
  float acc = 0.0f;

  const int e1 = rowp[node + 1];
  int e = rowp[node];
  for (; e + B <= e1; e += B) {
    int s[B];
#pragma unroll
    for (int j = 0; j < B; ++j) s[j] = csr[e + j];
    float wv[B];
#pragma unroll
    for (int j = 0; j < B; ++j) wv[j] = dinv[s[j]];
    float v[B];
#pragma unroll
    for (int j = 0; j < B; ++j)
      v[j] = act ? bf2f(Hs[(size_t)src_coloff + (size_t)s[j] * src_stride + off]) : 0.0f;
#pragma unroll
    for (int j = 0; j < B; ++j) acc += wv[j] * v[j];
  }
  for (; e < e1; ++e) {
    int s = csr[e];
    if (act) acc += dinv[s] * bf2f(Hs[(size_t)src_coloff + (size_t)s * src_stride + off]);
  }
  const float wi = dinv[node];
  if (act) acc += wi * bf2f(Hs[(size_t)src_coloff + (size_t)node * src_stride + off]);
  if (!act) return;
  float v = acc * wi;
  if (bias) v += bf2f(bias[off]);
  if (relu) v = fmaxf(v, 0.0f);
  size_t didx = (size_t)dst_coloff + (size_t)node * dst_stride + off;
  if (DSTF && of32) ((float*)Gb)[didx] = v;
  else ((u16*)Gb)[didx] = f2bf(v);
}

// ---------------- fast bf16 MFMA GEMM (m97 structure): C = A @ Bt^T ----------------
__global__ __launch_bounds__(256) void gemm_fast_kernel(
    const u16* __restrict__ A, int lda, const u16* __restrict__ Bt,
    u16* __restrict__ C, int ldc, const u16* __restrict__ bias,
    int M, int N, int K, int relu) {
  __shared__ __align__(16) u16 sA[128 * 64];
  __shared__ __align__(16) u16 sB[128 * 64];
  const int tid = threadIdx.x;
  const int lane = tid & 63;
  const int wave = __builtin_amdgcn_readfirstlane(tid >> 6);
  const int m0 = blockIdx.y * 128, n0 = blockIdx.x * 128;
  const int wm = (wave & 1) * 64, wn = (wave >> 1) * 64;
  const int lr = lane & 15, lq = lane >> 4;
  const int lrow = lane >> 3;
  const int lcol = (lane & 7) * 8;
  f32x4 acc[4][4] = {};

  for (int kb = 0; kb < K; kb += 64) {
#pragma unroll
    for (int it = 0; it < 4; ++it) {
      const int rbase = (it * 4 + wave) * 8;
      int gm = m0 + rbase + lrow;
      if (gm >= M) gm = M - 1;
      __builtin_amdgcn_global_load_lds(GLB_PTR(A + (size_t)gm * lda + kb + lcol),
                                       LDS_PTR(sA + rbase * 64), 16, 0, 0);
      const int gn = n0 + rbase + lrow;
      __builtin_amdgcn_global_load_lds(GLB_PTR(Bt + (size_t)gn * K + kb + lcol),
                                       LDS_PTR(sB + rbase * 64), 16, 0, 0);
    }
    __syncthreads();
#pragma unroll
    for (int ks = 0; ks < 2; ++ks) {
      bf16x8 af[4], bfr[4];
#pragma unroll
      for (int i = 0; i < 4; ++i)
        af[i] = *(const bf16x8*)(sA + (wm + i * 16 + lr) * 64 + ks * 32 + lq * 8);
#pragma unroll
      for (int i = 0; i < 4; ++i)
        bfr[i] = *(const bf16x8*)(sB + (wn + i * 16 + lr) * 64 + ks * 32 + lq * 8);
#pragma unroll
      for (int im = 0; im < 4; ++im)
#pragma unroll
        for (int in = 0; in < 4; ++in)
          acc[im][in] = __builtin_amdgcn_mfma_f32_16x16x32_bf16(af[im], bfr[in], acc[im][in], 0, 0, 0);
    }
    __syncthreads();
  }
#pragma unroll
  for (int im = 0; im < 4; ++im) {
#pragma unroll
    for (int in = 0; in < 4; ++in) {
      int col = n0 + wn + in * 16 + lr;
      float bv = bias ? bf2f(bias[col]) : 0.0f;
#pragma unroll
      for (int r = 0; r < 4; ++r) {
        int row = m0 + wm + im * 16 + lq * 4 + r;
        if (row < M) {
          float v = acc[im][in][r] + bv;
          if (relu) v = fmaxf(v, 0.0f);
          C[(size_t)row * ldc + col] = f2bf(v);
        }
      }
    }
  }
}

// ---------------- small/edge GEMM (padded-LDS, any K/N) ----------------
#define LP 72
__global__ __launch_bounds__(256) void gemm_small_kernel(
    const u16* __restrict__ A, int lda, const u16* __restrict__ Bt,
    u16* __restrict__ C, int ldc, const u16* __restrict__ bias,
    int M, int N, int K, int relu) {
  __shared__ __align__(16) u16 sA[128 * LP];
  __shared__ __align__(16) u16 sB[128 * LP];
  const int tid = threadIdx.x;
  const int lane = tid & 63, wave = tid >> 6;
  const int m0 = blockIdx.y * 128, n0 = blockIdx.x * 128;
  const int wm = (wave & 1) * 64, wn = (wave >> 1) * 64;
  const int lr = lane & 15;
  const int lq = lane >> 4;
  f32x4 acc[4][4] = {};

  for (int kb = 0; kb < K; kb += 64) {
#pragma unroll
    for (int it = 0; it < 4; ++it) {
      int linear = it * 2048 + tid * 8;
      int row = linear >> 6, kc = linear & 63;
      int gm = m0 + row, gk = kb + kc;
      int4 v = make_int4(0, 0, 0, 0);
      if (gm < M && gk < K) v = *(const int4*)(A + (size_t)gm * lda + gk);
      *(int4*)(sA + row * LP + kc) = v;
    }
#pragma unroll
    for (int it = 0; it < 4; ++it) {
      int linear = it * 2048 + tid * 8;
      int row = linear >> 6, kc = linear & 63;
      int gn = n0 + row, gk = kb + kc;
      int4 v = make_int4(0, 0, 0, 0);
      if (gn < N && gk < K) v = *(const int4*)(Bt + (size_t)gn * K + gk);
      *(int4*)(sB + row * LP + kc) = v;
    }
    __syncthreads();
#pragma unroll
    for (int ks = 0; ks < 2; ++ks) {
      bf16x8 af[4], bfr[4];
#pragma unroll
      for (int i = 0; i < 4; ++i)
        af[i] = *(const bf16x8*)(sA + (wm + i * 16 + lr) * LP + ks * 32 + lq * 8);
#pragma unroll
      for (int i = 0; i < 4; ++i)
        bfr[i] = *(const bf16x8*)(sB + (wn + i * 16 + lr) * LP + ks * 32 + lq * 8);
#pragma unroll
      for (int im = 0; im < 4; ++im)
#pragma unroll
        for (int in = 0; in < 4; ++in)
          acc[im][in] = __builtin_amdgcn_mfma_f32_16x16x32_bf16(af[im], bfr[in], acc[im][in], 0, 0, 0);
    }
    __syncthreads();
  }
#pragma unroll
  for (int im = 0; im < 4; ++im) {
#pragma unroll
    for (int in = 0; in < 4; ++in) {
      int col = n0 + wn + in * 16 + lr;
      if (col >= N) continue;
      float bv = bias ? bf2f(bias[col]) : 0.0f;
#pragma unroll
      for (int r = 0; r < 4; ++r) {
        int row = m0 + wm + im * 16 + lq * 4 + r;
        if (row < M) {
          float v = acc[im][in][r] + bv;
          if (relu) v = fmaxf(v, 0.0f);
          C[(size_t)row * ldc + col] = f2bf(v);
        }
      }
    }
  }
}

extern "C" void kernel_launch(void* const* d_in, const int* in_sizes, int n_in,
                              void* d_out, int out_size, void* d_ws, size_t ws_size,
                              hipStream_t stream) {
  const u16* x  = (const u16*)d_in[0];
  const int* ei = (const int*)d_in[1];

  const int Nn = in_sizes[0] / 32;   // 100000
  const int E  = in_sizes[1] / 2;    // 3200000
  const int CH = (Nn + 7) / 8;       // 12500
  const int NR = (Nn + CH - 1) / CH; // 8
  const int P  = ((Nn * 3 / 4) / 128) * 128;  // 74880
  const int NB = (Nn + (1 << BSH) - 1) >> BSH;  // 196 buckets

  char* w = (char*)d_ws;
  size_t off = 0;
  auto alloc = [&](size_t bytes) -> void* {
    void* p = w + off;
    off = (off + bytes + 255) & ~(size_t)255;
    return p;
  };
  int*   flags  = (int*)alloc(256);
  int*   gcur   = (int*)alloc(1024);
  int*   rowp   = (int*)alloc((size_t)(Nn + 1) * 4);
  int*   deg    = (int*)alloc((size_t)Nn * 4);
  float* dinv   = (float*)alloc((size_t)Nn * 4);
  int*   csr    = (int*)alloc((size_t)E * 4);
  u16*   Wt1    = (u16*)alloc((size_t)32 * 256 * 2);
  u16*   Wt2    = (u16*)alloc((size_t)256 * 1024 * 2);
  u16*   Wt3    = (u16*)alloc((size_t)1024 * 1024 * 2);
  u16*   Wt4    = (u16*)alloc((size_t)1024 * 256 * 2);
  u16*   Wt5    = (u16*)alloc((size_t)256 * 6 * 2);
  u16*   bc1    = (u16*)alloc(256 * 2);
  u16*   bc2    = (u16*)alloc(1024 * 2);
  u16*   bc3    = (u16*)alloc(1024 * 2);
  u16*   bc4    = (u16*)alloc(256 * 2);
  u16*   bc5    = (u16*)alloc(6 * 2);
  size_t selems = (size_t)CH * 1024;
  if ((size_t)Nn * 128 > selems) selems = (size_t)Nn * 128;
  u16*   S      = (u16*)alloc(selems * 2);             // 25.6 MB staging
  u16*   H      = (u16*)alloc((size_t)Nn * 1024 * 2);  // 204.8 MB main
  const size_t required = off;
  (void)n_in;

  if (ws_size < required) {
    if (ws_size >= 4096) {
      detect_x_kernel<<<1, 256, 0, stream>>>(x, flags);
      zero_out_kernel<<<(out_size + 255) / 256, 256, 0, stream>>>(d_out, out_size, flags);
    }
    return;
  }

  // pair scratch overlaid on H (free until CSR build completes)
  int2* pairs = (int2*)H;

  // ---- detection + bucketed CSR build ----
  detect_edge_kernel<<<1, 256, 0, stream>>>(ei, flags);
  detect_x_kernel<<<1, 256, 0, stream>>>(x, flags);
  zero_kernel<<<1, 256, 0, stream>>>(gcur, 256);
  bin_kernel<<<1024, 256, 0, stream>>>(ei, gcur, pairs, E, Nn, flags, 1024);
  bucket_count_kernel<<<NB, 256, 0, stream>>>(pairs, gcur, deg, Nn);
  scan_kernel<<<1, 1024, 0, stream>>>(deg, rowp, dinv, Nn);
  bucket_place_kernel<<<NB, 256, 0, stream>>>(pairs, gcur, rowp, csr, Nn);

  // ---- weights/biases -> bf16 [N,K] ----
  convert_w_kernel<<<(32 * 256 + 255) / 256, 256, 0, stream>>>(d_in[2], Wt1, 32, 256, flags);
  convert_w_kernel<<<1, 256, 0, stream>>>(d_in[3], bc1, 1, 256, flags);
  convert_w_kernel<<<(256 * 1024 + 255) / 256, 256, 0, stream>>>(d_in[4], Wt2, 256, 1024, flags);
  convert_w_kernel<<<4, 256, 0, stream>>>(d_in[5], bc2, 1, 1024, flags);
  convert_w_kernel<<<(1024 * 1024 + 255) / 256, 256, 0, stream>>>(d_in[6], Wt3, 1024, 1024, flags);
  convert_w_kernel<<<4, 256, 0, stream>>>(d_in[7], bc3, 1, 1024, flags);
  convert_w_kernel<<<(1024 * 256 + 255) / 256, 256, 0, stream>>>(d_in[8], Wt4, 1024, 256, flags);
  convert_w_kernel<<<1, 256, 0, stream>>>(d_in[9], bc4, 1, 256, flags);
  convert_w_kernel<<<(256 * 6 + 255) / 256, 256, 0, stream>>>(d_in[10], Wt5, 256, 6, flags);
  convert_w_kernel<<<1, 256, 0, stream>>>(d_in[11], bc5, 1, 6, flags);

  const int mb = (Nn + 127) / 128;
  const int sg6 = (Nn + 3) / 4;

  // L1: g1 = Â x -> S (Nn x 32, G=4, 16 nodes/wave); h1 = relu(g1@W1+b1) -> H (Nn x 256)
  spmm_wide_kernel<32, true><<<(Nn + 63) / 64, 256, 0, stream>>>(
      x, S, rowp, csr, dinv, nullptr, 0, Nn, 32, 0, 32, 0, flags);
  gemm_small_kernel<<<dim3(2, mb), 256, 0, stream>>>(S, 32, Wt1, H, 256, bc1, Nn, 256, 32, 1);

  // L2: g2 = Â h1 -> H tail block; h2 = relu(g2@W2+b2) -> H (two row ranges)
  spmm_wide_kernel<256, false><<<(Nn + 7) / 8, 256, 0, stream>>>(
      H, H, rowp, csr, dinv, nullptr, 0, Nn, 256, 0, 256, (long long)Nn * 768, flags);
  copyvec_kernel<<<(((Nn - P) * 256 / 8) + 255) / 256, 256, 0, stream>>>(
      (const int4*)(H + (size_t)Nn * 768 + (size_t)P * 256), (int4*)S, (Nn - P) * 256 / 8);
  gemm_fast_kernel<<<dim3(8, (P + 127) / 128), 256, 0, stream>>>(H + (size_t)Nn * 768, 256, Wt2, H,
                                                                 1024, bc2, P, 1024, 256, 1);
  gemm_fast_kernel<<<dim3(8, (Nn - P + 127) / 128), 256, 0, stream>>>(
      S, 256, Wt2, H + (size_t)P * 1024, 1024, bc2, Nn - P, 1024, 256, 1);

  // L3a: g3 = Â h2 in place in H, 8 column chunks of 128 via S (G=16, 4 nodes/wave)
  for (int c = 0; c < 8; ++c) {
    spmm_wide_kernel<128, false><<<(Nn + 15) / 16, 256, 0, stream>>>(
        H, S, rowp, csr, dinv, nullptr, 0, Nn, 1024, 128 * c, 128, 0, flags);
    copycols_kernel<<<(Nn * 16 + 255) / 256, 256, 0, stream>>>(S, H, 128 * c, Nn);
  }

  // L3b/L4a per row-chunk
  for (int R = 0; R < NR; ++R) {
    int MR = Nn - R * CH;
    if (MR > CH) MR = CH;
    u16* hR = H + (size_t)R * CH * 1024;
    int mbr = (MR + 127) / 128;
    gemm_fast_kernel<<<dim3(8, mbr), 256, 0, stream>>>(hR, 1024, Wt3, S, 1024, bc3, MR, 1024, 1024, 1);
    gemm_fast_kernel<<<dim3(2, mbr), 256, 0, stream>>>(S, 1024, Wt4, hR, 1024, nullptr, MR, 256, 1024, 0);
  }

  // L4b: h4 = relu(Â t4 + b4) -> H cols [256,512)  (read cols [0,256), stride 1024)
  spmm_wide_kernel<256, false><<<(Nn + 7) / 8, 256, 0, stream>>>(
      H, H, rowp, csr, dinv, bc4, 1, Nn, 1024, 0, 1024, 256, flags);

  // L5: t5 = h4@W5 -> S (Nn x 6); out = Â t5 + b5
  gemm_small_kernel<<<dim3(1, mb), 256, 0, stream>>>(H + 256, 1024, Wt5, S, 6, nullptr, Nn, 6, 256, 0);
  spmm_narrow_kernel<6, true><<<sg6, 256, 0, stream>>>(S, d_out, rowp, csr, dinv, bc5, 0, Nn,
                                                       6, 0, 6, 0, flags);
}

// Round 8
// 2426.714 us; speedup vs baseline: 1.2732x; 1.2732x over previous
//
#include <hip/hip_runtime.h>

typedef unsigned char u8;
typedef unsigned short u16;
typedef unsigned int u32;
typedef __bf16 bf16_t;
typedef bf16_t bf16x8 __attribute__((ext_vector_type(8)));
typedef float f32x4 __attribute__((ext_vector_type(4)));
typedef float f32x2 __attribute__((ext_vector_type(2)));

#define LDS_PTR(p) ((__attribute__((address_space(3))) unsigned int*)(p))
#define GLB_PTR(p) ((const __attribute__((address_space(1))) unsigned int*)(p))

#define BSH 9                 // bucket shift: 512 nodes per bucket
#define BCAP 32768            // pair capacity per bucket

static __device__ __forceinline__ float bf2f(u16 h) {
  u32 u = ((u32)h) << 16;
  return __builtin_bit_cast(float, u);
}
static __device__ __forceinline__ u16 f2bf(float f) {
  u32 u = __builtin_bit_cast(u32, f);
  u += 0x7fffu + ((u >> 16) & 1u);
  return (u16)(u >> 16);
}
static __device__ __forceinline__ void accum_d(float* acc, int j, u32 d, float w) {
  float lo = __builtin_bit_cast(float, d << 16);
  float hi = __builtin_bit_cast(float, d & 0xffff0000u);
  acc[j] += w * lo;
  acc[j + 1] += w * hi;
}

// ---------------- detection ----------------
__global__ void detect_edge_kernel(const int* __restrict__ ei, int* __restrict__ flags) {
  __shared__ int nz;
  if (threadIdx.x == 0) nz = 0;
  __syncthreads();
  if (ei[1 + 2 * threadIdx.x] != 0) atomicAdd(&nz, 1);
  __syncthreads();
  if (threadIdx.x == 0) flags[0] = (nz == 0) ? 1 : 0;
}

__global__ void detect_x_kernel(const u16* __restrict__ x, int* __restrict__ flags) {
  __shared__ int cnt;
  if (threadIdx.x == 0) cnt = 0;
  __syncthreads();
  u32 u = x[threadIdx.x];
  u32 e = (u >> 7) & 0xFF;
  if (e >= 0x60 && e <= 0x83) atomicAdd(&cnt, 1);
  __syncthreads();
  if (threadIdx.x == 0) flags[1] = (cnt >= 240) ? 0 : 1;
}

static __device__ __forceinline__ int eidx(const void* ei, size_t i, int m) {
  return m ? (int)((const long long*)ei)[i] : ((const int*)ei)[i];
}

// ---------------- utility ----------------
__global__ void zero_kernel(int* __restrict__ p, int n) {
  int i = blockIdx.x * 256 + threadIdx.x;
  if (i < n) p[i] = 0;
}

__global__ void zero_out_kernel(void* __restrict__ out, int n, const int* __restrict__ flags) {
  int i = blockIdx.x * 256 + threadIdx.x;
  if (i < n) {
    if (flags[1]) ((float*)out)[i] = 0.0f;
    else ((u16*)out)[i] = 0;
  }
}

__global__ void convert_w_kernel(const void* __restrict__ W, u16* __restrict__ Wt,
                                 int K, int N, const int* __restrict__ flags) {
  int idx = blockIdx.x * 256 + threadIdx.x;
  if (idx < K * N) {
    int k = idx / N, n = idx % N;
    float v = flags[1] ? ((const float*)W)[idx] : bf2f(((const u16*)W)[idx]);
    Wt[n * K + k] = f2bf(v);
  }
}

// ---------------- bucketed CSR build ----------------
__global__ __launch_bounds__(256) void bin_kernel(const void* __restrict__ ei,
                                                  int* __restrict__ gcur,
                                                  int2* __restrict__ pairs, int E, int Nn,
                                                  const int* __restrict__ flags, int nblk) {
  __shared__ int h[256];
  __shared__ int base[256];
  const int m = flags[0];
  const int nb = (Nn + (1 << BSH) - 1) >> BSH;
  const int per = (E + nblk - 1) / nblk;
  const int e0 = blockIdx.x * per;
  const int e1 = (e0 + per < E) ? e0 + per : E;
  for (int i = threadIdx.x; i < nb; i += 256) h[i] = 0;
  __syncthreads();
  for (int e = e0 + threadIdx.x; e < e1; e += 256) {
    int d = eidx(ei, (size_t)E + e, m);
    if ((u32)d < (u32)Nn) atomicAdd(&h[d >> BSH], 1);
  }
  __syncthreads();
  for (int i = threadIdx.x; i < nb; i += 256) {
    base[i] = atomicAdd(&gcur[i], h[i]);
    h[i] = 0;
  }
  __syncthreads();
  for (int e = e0 + threadIdx.x; e < e1; e += 256) {
    int d = eidx(ei, (size_t)E + e, m);
    if ((u32)d >= (u32)Nn) continue;
    int s = eidx(ei, (size_t)e, m);
    if ((u32)s >= (u32)Nn) s = 0;
    int b = d >> BSH;
    int p = base[b] + atomicAdd(&h[b], 1);
    if (p < BCAP) pairs[(size_t)b * BCAP + p] = make_int2(s, d);
  }
}

__global__ __launch_bounds__(256) void bucket_count_kernel(const int2* __restrict__ pairs,
                                                           const int* __restrict__ gcur,
                                                           int* __restrict__ deg, int Nn) {
  __shared__ int cnt[1 << BSH];
  const int b = blockIdx.x;
  const int n0 = b << BSH;
  for (int j = threadIdx.x; j < (1 << BSH); j += 256) cnt[j] = 0;
  __syncthreads();
  int tot = gcur[b];
  if (tot > BCAP) tot = BCAP;
  for (int i = threadIdx.x; i < tot; i += 256) {
    int2 pr = pairs[(size_t)b * BCAP + i];
    atomicAdd(&cnt[pr.y - n0], 1);
  }
  __syncthreads();
  for (int j = threadIdx.x; j < (1 << BSH); j += 256) {
    int node = n0 + j;
    if (node < Nn) deg[node] = cnt[j];
  }
}

__global__ __launch_bounds__(1024) void scan_kernel(const int* __restrict__ deg,
                                                    int* __restrict__ rowp,
                                                    float* __restrict__ dinv, int Nn) {
  __shared__ int sd[1024];
  int tid = threadIdx.x;
  int carry = 0;
  if (tid == 0) rowp[0] = 0;
  for (int base = 0; base < Nn; base += 4096) {
    int i0 = base + tid * 4;
    int v[4];
    int tot = 0;
#pragma unroll
    for (int j = 0; j < 4; ++j) {
      v[j] = (i0 + j < Nn) ? deg[i0 + j] : 0;
      tot += v[j];
    }
    sd[tid] = tot;
    __syncthreads();
    for (int s = 1; s < 1024; s <<= 1) {
      int t = (tid >= s) ? sd[tid - s] : 0;
      __syncthreads();
      sd[tid] += t;
      __syncthreads();
    }
    int run = carry + sd[tid] - tot;
#pragma unroll
    for (int j = 0; j < 4; ++j) {
      if (i0 + j < Nn) {
        dinv[i0 + j] = rsqrtf((float)(v[j] + 1));  // +1 self loop
        run += v[j];
        rowp[i0 + j + 1] = run;
      }
    }
    carry += sd[1023];
    __syncthreads();
  }
}

__global__ __launch_bounds__(256) void bucket_place_kernel(const int2* __restrict__ pairs,
                                                           const int* __restrict__ gcur,
                                                           const int* __restrict__ rowp,
                                                           int* __restrict__ csr, int Nn) {
  __shared__ int cur[1 << BSH];
  const int b = blockIdx.x;
  const int n0 = b << BSH;
  for (int j = threadIdx.x; j < (1 << BSH); j += 256) {
    int node = n0 + j;
    cur[j] = (node < Nn) ? rowp[node] : 0;
  }
  __syncthreads();
  int tot = gcur[b];
  if (tot > BCAP) tot = BCAP;
  for (int i = threadIdx.x; i < tot; i += 256) {
    int2 pr = pairs[(size_t)b * BCAP + i];
    int p = atomicAdd(&cur[pr.y - n0], 1);
    csr[p] = pr.x;
  }
}

// ---------------- pull-SpMM (R6 form: wave-per-node, 16-deep batch, scalar indices) ----------------
template <int W, bool SRCF, bool DSTF>
__global__ __launch_bounds__(256) void spmm_kernel(
    const void* __restrict__ Hb, void* __restrict__ Gb,
    const int* __restrict__ rowp, const int* __restrict__ csr,
    const float* __restrict__ dinv, const u16* __restrict__ bias,
    int relu, int Nn, int src_stride, long long src_coloff,
    int dst_stride, long long dst_coloff, const int* __restrict__ flags) {
  constexpr int VPL = (W >= 64) ? (W / 64) : 1;
  constexpr int B = 16;
  const int lane = threadIdx.x & 63;
  const int node = __builtin_amdgcn_readfirstlane(blockIdx.x * 4 + (threadIdx.x >> 6));
  if (node >= Nn) return;
  const bool act = (W >= 64) || (lane < W);
  const int off = (W >= 64) ? lane * VPL : lane;
  int sf32 = 0, of32 = 0;
  if (SRCF) sf32 = flags[1];
  if (DSTF) of32 = flags[1];
  const u16* Hs = (const u16*)Hb;
  float acc[VPL];
#pragma unroll
  for (int j = 0; j < VPL; ++j) acc[j] = 0.0f;

  auto srcidx = [&](int s) -> size_t {
    return (size_t)src_coloff + (size_t)s * src_stride + off;
  };
  auto accum_row = [&](int s, float w) {
    if (!act) return;
    size_t idx = srcidx(s);
    if constexpr (W == 256) {
      int2 v = *(const int2*)(Hs + idx);
      accum_d(acc, 0, (u32)v.x, w);
      accum_d(acc, 2, (u32)v.y, w);
    } else {
      float val = (SRCF && sf32) ? ((const float*)Hb)[idx] : bf2f(Hs[idx]);
      acc[0] += w * val;
    }
  };

  const int e1 = rowp[node + 1];
  int e = rowp[node];

  for (; e + B <= e1; e += B) {
    int s[B];
#pragma unroll
    for (int j = 0; j < B; ++j) s[j] = csr[e + j];
    float wv[B];
#pragma unroll
    for (int j = 0; j < B; ++j) wv[j] = dinv[s[j]];
    if constexpr (W == 256) {
      int2 v[B];
#pragma unroll
      for (int j = 0; j < B; ++j) v[j] = *(const int2*)(Hs + srcidx(s[j]));
      if (act) {
#pragma unroll
        for (int j = 0; j < B; ++j) {
          accum_d(acc, 0, (u32)v[j].x, wv[j]);
          accum_d(acc, 2, (u32)v[j].y, wv[j]);
        }
      }
    } else {
      float v[B];
#pragma unroll
      for (int j = 0; j < B; ++j) {
        size_t idx = srcidx(s[j]);
        v[j] = (SRCF && sf32) ? ((const float*)Hb)[idx] : bf2f(Hs[idx]);
      }
      if (act) {
#pragma unroll
        for (int j = 0; j < B; ++j) acc[0] += wv[j] * v[j];
      }
    }
  }
  for (; e < e1; ++e) {
    int s = csr[e];
    accum_row(s, dinv[s]);
  }
  const float wi = dinv[node];
  accum_row(node, wi);
  if (!act) return;

  float vals[VPL];
#pragma unroll
  for (int j = 0; j < VPL; ++j) {
    float v = acc[j] * wi;
    if (bias) v += bf2f(bias[off + j]);
    if (relu) v = fmaxf(v, 0.0f);
    vals[j] = v;
  }
  size_t didx = (size_t)dst_coloff + (size_t)node * dst_stride + off;
  if constexpr (W == 256) {
    u32 d0 = (u32)f2bf(vals[0]) | ((u32)f2bf(vals[1]) << 16);
    u32 d1 = (u32)f2bf(vals[2]) | ((u32)f2bf(vals[3]) << 16);
    *(int2*)((u16*)Gb + didx) = make_int2((int)d0, (int)d1);
  } else {
    if (DSTF && of32) ((float*)Gb)[didx] = vals[0];
    else ((u16*)Gb)[didx] = f2bf(vals[0]);
  }
}

// ---------------- fp8 pull-SpMM, W=1024, one wave per node, 16 fp8 cols/lane ----------------
// g3[node] = dinv[node]*(sum dinv[s]*h2q[s] + dinv[node]*h2q[node]); nodes in [n0,n1); out bf16.
__global__ __launch_bounds__(256) void spmm_fp8_kernel(
    const u8* __restrict__ Hq, u16* __restrict__ G,
    const int* __restrict__ rowp, const int* __restrict__ csr,
    const float* __restrict__ dinv, int n0, int n1) {
  const int lane = threadIdx.x & 63;
  const int node = __builtin_amdgcn_readfirstlane(n0 + blockIdx.x * 4 + (threadIdx.x >> 6));
  if (node >= n1) return;
  const int off = lane * 16;  // byte offset == col offset
  float acc[16];
#pragma unroll
  for (int k = 0; k < 16; ++k) acc[k] = 0.0f;

  auto dec = [&](int4 v, float w) {
#pragma unroll
    for (int q = 0; q < 4; ++q) {
      int d = (q == 0) ? v.x : (q == 1) ? v.y : (q == 2) ? v.z : v.w;
      f32x2 a = __builtin_amdgcn_cvt_pk_f32_fp8(d, false);
      f32x2 b = __builtin_amdgcn_cvt_pk_f32_fp8(d, true);
      acc[q * 4 + 0] += w * a.x;
      acc[q * 4 + 1] += w * a.y;
      acc[q * 4 + 2] += w * b.x;
      acc[q * 4 + 3] += w * b.y;
    }
  };

  const int e1r = rowp[node + 1];
  int e = rowp[node];
  for (; e + 8 <= e1r; e += 8) {
    int s[8];
#pragma unroll
    for (int j = 0; j < 8; ++j) s[j] = csr[e + j];
    float wv[8];
#pragma unroll
    for (int j = 0; j < 8; ++j) wv[j] = dinv[s[j]];
    int4 v[8];
#pragma unroll
    for (int j = 0; j < 8; ++j) v[j] = *(const int4*)(Hq + (size_t)s[j] * 1024 + off);
#pragma unroll
    for (int j = 0; j < 8; ++j) dec(v[j], wv[j]);
  }
  for (; e < e1r; ++e) {
    int s = csr[e];
    dec(*(const int4*)(Hq + (size_t)s * 1024 + off), dinv[s]);
  }
  const float wi = dinv[node];
  dec(*(const int4*)(Hq + (size_t)node * 1024 + off), wi);

  u32 d[8];
#pragma unroll
  for (int k = 0; k < 8; ++k) {
    float v0 = acc[2 * k] * wi, v1 = acc[2 * k + 1] * wi;
    d[k] = (u32)f2bf(v0) | ((u32)f2bf(v1) << 16);
  }
  u16* gp = G + (size_t)(node - n0) * 1024 + off;
  ((int4*)gp)[0] = make_int4((int)d[0], (int)d[1], (int)d[2], (int)d[3]);
  ((int4*)gp)[1] = make_int4((int)d[4], (int)d[5], (int)d[6], (int)d[7]);
}

// ---------------- fast bf16 MFMA GEMM (m97 structure): C = A @ Bt^T ----------------
// Requires K%64==0, N%128==0. fp8out: C treated as u8* with ldc in bytes.
__global__ __launch_bounds__(256) void gemm_fast_kernel(
    const u16* __restrict__ A, int lda, const u16* __restrict__ Bt,
    u16* __restrict__ C, int ldc, const u16* __restrict__ bias,
    int M, int N, int K, int relu, int fp8out) {
  __shared__ __align__(16) u16 sA[128 * 64];
  __shared__ __align__(16) u16 sB[128 * 64];
  const int tid = threadIdx.x;
  const int lane = tid & 63;
  const int wave = __builtin_amdgcn_readfirstlane(tid >> 6);
  const int m0 = blockIdx.y * 128, n0 = blockIdx.x * 128;
  const int wm = (wave & 1) * 64, wn = (wave >> 1) * 64;
  const int lr = lane & 15, lq = lane >> 4;
  const int lrow = lane >> 3;
  const int lcol = (lane & 7) * 8;
  f32x4 acc[4][4] = {};

  for (int kb = 0; kb < K; kb += 64) {
#pragma unroll
    for (int it = 0; it < 4; ++it) {
      const int rbase = (it * 4 + wave) * 8;
      int gm = m0 + rbase + lrow;
      if (gm >= M) gm = M - 1;
      __builtin_amdgcn_global_load_lds(GLB_PTR(A + (size_t)gm * lda + kb + lcol),
                                       LDS_PTR(sA + rbase * 64), 16, 0, 0);
      const int gn = n0 + rbase + lrow;
      __builtin_amdgcn_global_load_lds(GLB_PTR(Bt + (size_t)gn * K + kb + lcol),
                                       LDS_PTR(sB + rbase * 64), 16, 0, 0);
    }
    __syncthreads();
#pragma unroll
    for (int ks = 0; ks < 2; ++ks) {
      bf16x8 af[4], bfr[4];
#pragma unroll
      for (int i = 0; i < 4; ++i)
        af[i] = *(const bf16x8*)(sA + (wm + i * 16 + lr) * 64 + ks * 32 + lq * 8);
#pragma unroll
      for (int i = 0; i < 4; ++i)
        bfr[i] = *(const bf16x8*)(sB + (wn + i * 16 + lr) * 64 + ks * 32 + lq * 8);
#pragma unroll
      for (int im = 0; im < 4; ++im)
#pragma unroll
        for (int in = 0; in < 4; ++in)
          acc[im][in] = __builtin_amdgcn_mfma_f32_16x16x32_bf16(af[im], bfr[in], acc[im][in], 0, 0, 0);
    }
    __syncthreads();
  }
#pragma unroll
  for (int im = 0; im < 4; ++im) {
#pragma unroll
    for (int in = 0; in < 4; ++in) {
      int col = n0 + wn + in * 16 + lr;
      float bv = bias ? bf2f(bias[col]) : 0.0f;
#pragma unroll
      for (int r = 0; r < 4; ++r) {
        int row = m0 + wm + im * 16 + lq * 4 + r;
        if (row < M) {
          float v = acc[im][in][r] + bv;
          if (relu) v = fmaxf(v, 0.0f);
          if (fp8out) {
            int pk = __builtin_amdgcn_cvt_pk_fp8_f32(v, v, 0, false);
            ((u8*)C)[(size_t)row * ldc + col] = (u8)(pk & 0xff);
          } else {
            C[(size_t)row * ldc + col] = f2bf(v);
          }
        }
      }
    }
  }
}

// ---------------- small/edge GEMM (padded-LDS, any K/N) ----------------
#define LP 72
__global__ __launch_bounds__(256) void gemm_small_kernel(
    const u16* __restrict__ A, int lda, const u16* __restrict__ Bt,
    u16* __restrict__ C, int ldc, const u16* __restrict__ bias,
    int M, int N, int K, int relu) {
  __shared__ __align__(16) u16 sA[128 * LP];
  __shared__ __align__(16) u16 sB[128 * LP];
  const int tid = threadIdx.x;
  const int lane = tid & 63, wave = tid >> 6;
  const int m0 = blockIdx.y * 128, n0 = blockIdx.x * 128;
  const int wm = (wave & 1) * 64, wn = (wave >> 1) * 64;
  const int lr = lane & 15;
  const int lq = lane >> 4;
  f32x4 acc[4][4] = {};

  for (int kb = 0; kb < K; kb += 64) {
#pragma unroll
    for (int it = 0; it < 4; ++it) {
      int linear = it * 2048 + tid * 8;
      int row = linear >> 6, kc = linear & 63;
      int gm = m0 + row, gk = kb + kc;
      int4 v = make_int4(0, 0, 0, 0);
      if (gm < M && gk < K) v = *(const int4*)(A + (size_t)gm * lda + gk);
      *(int4*)(sA + row * LP + kc) = v;
    }
#pragma unroll
    for (int it = 0; it < 4; ++it) {
      int linear = it * 2048 + tid * 8;
      int row = linear >> 6, kc = linear & 63;
      int gn = n0 + row, gk = kb + kc;
      int4 v = make_int4(0, 0, 0, 0);
      if (gn < N && gk < K) v = *(const int4*)(Bt + (size_t)gn * K + gk);
      *(int4*)(sB + row * LP + kc) = v;
    }
    __syncthreads();
#pragma unroll
    for (int ks = 0; ks < 2; ++ks) {
      bf16x8 af[4], bfr[4];
#pragma unroll
      for (int i = 0; i < 4; ++i)
        af[i] = *(const bf16x8*)(sA + (wm + i * 16 + lr) * LP + ks * 32 + lq * 8);
#pragma unroll
      for (int i = 0; i < 4; ++i)
        bfr[i] = *(const bf16x8*)(sB + (wn + i * 16 + lr) * LP + ks * 32 + lq * 8);
#pragma unroll
      for (int im = 0; im < 4; ++im)
#pragma unroll
        for (int in = 0; in < 4; ++in)
          acc[im][in] = __builtin_amdgcn_mfma_f32_16x16x32_bf16(af[im], bfr[in], acc[im][in], 0, 0, 0);
    }
    __syncthreads();
  }
#pragma unroll
  for (int im = 0; im < 4; ++im) {
#pragma unroll
    for (int in = 0; in < 4; ++in) {
      int col = n0 + wn + in * 16 + lr;
      if (col >= N) continue;
      float bv = bias ? bf2f(bias[col]) : 0.0f;
#pragma unroll
      for (int r = 0; r < 4; ++r) {
        int row = m0 + wm + im * 16 + lq * 4 + r;
        if (row < M) {
          float v = acc[im][in][r] + bv;
          if (relu) v = fmaxf(v, 0.0f);
          C[(size_t)row * ldc + col] = f2bf(v);
        }
      }
    }
  }
}

extern "C" void kernel_launch(void* const* d_in, const int* in_sizes, int n_in,
                              void* d_out, int out_size, void* d_ws, size_t ws_size,
                              hipStream_t stream) {
  const u16* x  = (const u16*)d_in[0];
  const int* ei = (const int*)d_in[1];

  const int Nn = in_sizes[0] / 32;   // 100000
  const int E  = in_sizes[1] / 2;    // 3200000
  const int CH = (Nn + 7) / 8;       // 12500
  const int NR = (Nn + CH - 1) / CH; // 8
  const int NB = (Nn + (1 << BSH) - 1) >> BSH;  // 196 buckets

  char* w = (char*)d_ws;
  size_t off = 0;
  auto alloc = [&](size_t bytes) -> void* {
    void* p = w + off;
    off = (off + bytes + 255) & ~(size_t)255;
    return p;
  };
  int*   flags  = (int*)alloc(256);
  int*   gcur   = (int*)alloc(1024);
  int*   rowp   = (int*)alloc((size_t)(Nn + 1) * 4);
  int*   deg    = (int*)alloc((size_t)Nn * 4);
  float* dinv   = (float*)alloc((size_t)Nn * 4);
  int*   csr    = (int*)alloc((size_t)E * 4);
  u16*   Wt1    = (u16*)alloc((size_t)32 * 256 * 2);
  u16*   Wt2    = (u16*)alloc((size_t)256 * 1024 * 2);
  u16*   Wt3    = (u16*)alloc((size_t)1024 * 1024 * 2);
  u16*   Wt4    = (u16*)alloc((size_t)1024 * 256 * 2);
  u16*   Wt5    = (u16*)alloc((size_t)256 * 6 * 2);
  u16*   bc1    = (u16*)alloc(256 * 2);
  u16*   bc2    = (u16*)alloc(1024 * 2);
  u16*   bc3    = (u16*)alloc(1024 * 2);
  u16*   bc4    = (u16*)alloc(256 * 2);
  u16*   bc5    = (u16*)alloc(6 * 2);
  size_t selems = (size_t)CH * 1024;
  if ((size_t)Nn * 128 > selems) selems = (size_t)Nn * 128;
  u16*   S      = (u16*)alloc(selems * 2);             // 25.6 MB staging
  u16*   H      = (u16*)alloc((size_t)Nn * 1024 * 2);  // 204.8 MB main
  const size_t required = off;
  (void)n_in;

  if (ws_size < required) {
    if (ws_size >= 4096) {
      detect_x_kernel<<<1, 256, 0, stream>>>(x, flags);
      zero_out_kernel<<<(out_size + 255) / 256, 256, 0, stream>>>(d_out, out_size, flags);
    }
    return;
  }

  // H sub-regions (u16 element offsets):
  //   h2q  : fp8, bytes [0, Nn*1024)          == u16 [0, Nn*512)
  //   g2/t4: u16 [Nn*512, Nn*768)             (g2 dead after W2 -> t4 reuses)
  //   h1/h3_R/h4: u16 [Nn*768, Nn*1024)
  u8*  h2q = (u8*)H;
  u16* g2  = H + (size_t)Nn * 512;
  u16* t4  = H + (size_t)Nn * 512;
  u16* h1  = H + (size_t)Nn * 768;
  u16* h3R = H + (size_t)Nn * 768;
  u16* h4  = H + (size_t)Nn * 768;

  // pair scratch overlaid on H (dead until CSR build completes)
  int2* pairs = (int2*)H;

  // ---- detection + bucketed CSR build ----
  detect_edge_kernel<<<1, 256, 0, stream>>>(ei, flags);
  detect_x_kernel<<<1, 256, 0, stream>>>(x, flags);
  zero_kernel<<<1, 256, 0, stream>>>(gcur, 256);
  bin_kernel<<<1024, 256, 0, stream>>>(ei, gcur, pairs, E, Nn, flags, 1024);
  bucket_count_kernel<<<NB, 256, 0, stream>>>(pairs, gcur, deg, Nn);
  scan_kernel<<<1, 1024, 0, stream>>>(deg, rowp, dinv, Nn);
  bucket_place_kernel<<<NB, 256, 0, stream>>>(pairs, gcur, rowp, csr, Nn);

  // ---- weights/biases -> bf16 [N,K] ----
  convert_w_kernel<<<(32 * 256 + 255) / 256, 256, 0, stream>>>(d_in[2], Wt1, 32, 256, flags);
  convert_w_kernel<<<1, 256, 0, stream>>>(d_in[3], bc1, 1, 256, flags);
  convert_w_kernel<<<(256 * 1024 + 255) / 256, 256, 0, stream>>>(d_in[4], Wt2, 256, 1024, flags);
  convert_w_kernel<<<4, 256, 0, stream>>>(d_in[5], bc2, 1, 1024, flags);
  convert_w_kernel<<<(1024 * 1024 + 255) / 256, 256, 0, stream>>>(d_in[6], Wt3, 1024, 1024, flags);
  convert_w_kernel<<<4, 256, 0, stream>>>(d_in[7], bc3, 1, 1024, flags);
  convert_w_kernel<<<(1024 * 256 + 255) / 256, 256, 0, stream>>>(d_in[8], Wt4, 1024, 256, flags);
  convert_w_kernel<<<1, 256, 0, stream>>>(d_in[9], bc4, 1, 256, flags);
  convert_w_kernel<<<(256 * 6 + 255) / 256, 256, 0, stream>>>(d_in[10], Wt5, 256, 6, flags);
  convert_w_kernel<<<1, 256, 0, stream>>>(d_in[11], bc5, 1, 6, flags);

  const int sg = (Nn + 3) / 4;
  const int mb = (Nn + 127) / 128;

  // L1: g1 = Â x -> S (Nn x 32); h1 = relu(g1@W1+b1) -> h1 (Nn x 256)
  spmm_kernel<32, true, false><<<sg, 256, 0, stream>>>(x, S, rowp, csr, dinv, nullptr, 0, Nn,
                                                       32, 0, 32, 0, flags);
  gemm_small_kernel<<<dim3(2, mb), 256, 0, stream>>>(S, 32, Wt1, h1, 256, bc1, Nn, 256, 32, 1);

  // L2: g2 = Â h1 -> g2 region; h2 = relu(g2@W2+b2) -> fp8 in h2q
  spmm_kernel<256, false, false><<<sg, 256, 0, stream>>>(
      H, H, rowp, csr, dinv, nullptr, 0, Nn, 256, (long long)Nn * 768, 256, (long long)Nn * 512,
      flags);
  gemm_fast_kernel<<<dim3(8, mb), 256, 0, stream>>>(g2, 256, Wt2, (u16*)h2q, 1024, bc2,
                                                    Nn, 1024, 256, 1, 1);

  // L3+L4a per row-chunk: g3_R = Â h2q (fp8 gather, W=1024) -> S;
  //   h3_R = relu(g3_R@W3+b3) -> h3R; t4_R = h3_R@W4 -> t4[R]
  for (int R = 0; R < NR; ++R) {
    int n0 = R * CH;
    int n1 = n0 + CH < Nn ? n0 + CH : Nn;
    int MR = n1 - n0;
    int mbr = (MR + 127) / 128;
    spmm_fp8_kernel<<<(MR + 3) / 4, 256, 0, stream>>>(h2q, S, rowp, csr, dinv, n0, n1);
    gemm_fast_kernel<<<dim3(8, mbr), 256, 0, stream>>>(S, 1024, Wt3, h3R, 1024, bc3,
                                                       MR, 1024, 1024, 1, 0);
    gemm_fast_kernel<<<dim3(2, mbr), 256, 0, stream>>>(h3R, 1024, Wt4, t4 + (size_t)n0 * 256, 256,
                                                       nullptr, MR, 256, 1024, 0, 0);
  }

  // L4b: h4 = relu(Â t4 + b4) -> h4 region
  spmm_kernel<256, false, false><<<sg, 256, 0, stream>>>(
      H, H, rowp, csr, dinv, bc4, 1, Nn, 256, (long long)Nn * 512, 256, (long long)Nn * 768,
      flags);

  // L5: t5 = h4@W5 -> S (Nn x 6); out = Â t5 + b5
  gemm_small_kernel<<<dim3(1, mb), 256, 0, stream>>>(h4, 256, Wt5, S, 6, nullptr, Nn, 6, 256, 0);
  spmm_kernel<6, false, true><<<sg, 256, 0, stream>>>(S, d_out, rowp, csr, dinv, bc5, 0, Nn,
                                                      6, 0, 6, 0, flags);
}

// Round 9
// 2215.066 us; speedup vs baseline: 1.3949x; 1.0955x over previous
//
#include <hip/hip_runtime.h>

typedef unsigned char u8;
typedef unsigned short u16;
typedef unsigned int u32;
typedef __bf16 bf16_t;
typedef bf16_t bf16x8 __attribute__((ext_vector_type(8)));
typedef float f32x4 __attribute__((ext_vector_type(4)));
typedef float f32x2 __attribute__((ext_vector_type(2)));

#define LDS_PTR(p) ((__attribute__((address_space(3))) unsigned int*)(p))
#define GLB_PTR(p) ((const __attribute__((address_space(1))) unsigned int*)(p))

#define BSH 9                 // bucket shift: 512 nodes per bucket
#define BCAP 32768            // pair capacity per bucket

static __device__ __forceinline__ float bf2f(u16 h) {
  u32 u = ((u32)h) << 16;
  return __builtin_bit_cast(float, u);
}
static __device__ __forceinline__ u16 f2bf(float f) {
  u32 u = __builtin_bit_cast(u32, f);
  u += 0x7fffu + ((u >> 16) & 1u);
  return (u16)(u >> 16);
}
static __device__ __forceinline__ void accum_d(float* acc, int j, u32 d, float w) {
  float lo = __builtin_bit_cast(float, d << 16);
  float hi = __builtin_bit_cast(float, d & 0xffff0000u);
  acc[j] += w * lo;
  acc[j + 1] += w * hi;
}

// ---------------- detection ----------------
__global__ void detect_edge_kernel(const int* __restrict__ ei, int* __restrict__ flags) {
  __shared__ int nz;
  if (threadIdx.x == 0) nz = 0;
  __syncthreads();
  if (ei[1 + 2 * threadIdx.x] != 0) atomicAdd(&nz, 1);
  __syncthreads();
  if (threadIdx.x == 0) flags[0] = (nz == 0) ? 1 : 0;
}

__global__ void detect_x_kernel(const u16* __restrict__ x, int* __restrict__ flags) {
  __shared__ int cnt;
  if (threadIdx.x == 0) cnt = 0;
  __syncthreads();
  u32 u = x[threadIdx.x];
  u32 e = (u >> 7) & 0xFF;
  if (e >= 0x60 && e <= 0x83) atomicAdd(&cnt, 1);
  __syncthreads();
  if (threadIdx.x == 0) flags[1] = (cnt >= 240) ? 0 : 1;
}

static __device__ __forceinline__ int eidx(const void* ei, size_t i, int m) {
  return m ? (int)((const long long*)ei)[i] : ((const int*)ei)[i];
}

// ---------------- utility ----------------
__global__ void zero_kernel(int* __restrict__ p, int n) {
  int i = blockIdx.x * 256 + threadIdx.x;
  if (i < n) p[i] = 0;
}

__global__ void zero_out_kernel(void* __restrict__ out, int n, const int* __restrict__ flags) {
  int i = blockIdx.x * 256 + threadIdx.x;
  if (i < n) {
    if (flags[1]) ((float*)out)[i] = 0.0f;
    else ((u16*)out)[i] = 0;
  }
}

// transpose + convert to bf16; lgN>=0 -> N is 1<<lgN (shift path)
__global__ void convert_w_kernel(const void* __restrict__ W, u16* __restrict__ Wt,
                                 int K, int N, int lgN, const int* __restrict__ flags) {
  int idx = blockIdx.x * 256 + threadIdx.x;
  if (idx < K * N) {
    int k, n;
    if (lgN >= 0) { k = idx >> lgN; n = idx & (N - 1); }
    else { k = idx / N; n = idx % N; }
    float v = flags[1] ? ((const float*)W)[idx] : bf2f(((const u16*)W)[idx]);
    Wt[n * K + k] = f2bf(v);
  }
}

// ---------------- bucketed CSR build ----------------
__global__ __launch_bounds__(256) void bin_kernel(const void* __restrict__ ei,
                                                  int* __restrict__ gcur,
                                                  int2* __restrict__ pairs, int E, int Nn,
                                                  const int* __restrict__ flags, int nblk) {
  __shared__ int h[256];
  __shared__ int base[256];
  const int m = flags[0];
  const int nb = (Nn + (1 << BSH) - 1) >> BSH;
  const int per = (E + nblk - 1) / nblk;
  const int e0 = blockIdx.x * per;
  const int e1 = (e0 + per < E) ? e0 + per : E;
  for (int i = threadIdx.x; i < nb; i += 256) h[i] = 0;
  __syncthreads();
  for (int e = e0 + threadIdx.x; e < e1; e += 256) {
    int d = eidx(ei, (size_t)E + e, m);
    if ((u32)d < (u32)Nn) atomicAdd(&h[d >> BSH], 1);
  }
  __syncthreads();
  for (int i = threadIdx.x; i < nb; i += 256) {
    base[i] = atomicAdd(&gcur[i], h[i]);
    h[i] = 0;
  }
  __syncthreads();
  for (int e = e0 + threadIdx.x; e < e1; e += 256) {
    int d = eidx(ei, (size_t)E + e, m);
    if ((u32)d >= (u32)Nn) continue;
    int s = eidx(ei, (size_t)e, m);
    if ((u32)s >= (u32)Nn) s = 0;
    int b = d >> BSH;
    int p = base[b] + atomicAdd(&h[b], 1);
    if (p < BCAP) pairs[(size_t)b * BCAP + p] = make_int2(s, d);
  }
}

// exclusive scan over NB (<=256) bucket totals
__global__ __launch_bounds__(256) void bucket_scan_kernel(const int* __restrict__ gcur,
                                                          int* __restrict__ gbase, int NB) {
  __shared__ int sd[256];
  int tid = threadIdx.x;
  int v = (tid < NB) ? gcur[tid] : 0;
  if (v > BCAP) v = BCAP;
  sd[tid] = v;
  __syncthreads();
  for (int s = 1; s < 256; s <<= 1) {
    int t = (tid >= s) ? sd[tid - s] : 0;
    __syncthreads();
    sd[tid] += t;
    __syncthreads();
  }
  if (tid < NB) gbase[tid] = sd[tid] - v;
}

// per-bucket: histogram -> local scan -> rowp/dinv -> place csr
__global__ __launch_bounds__(512) void bucket_finalize_kernel(
    const int2* __restrict__ pairs, const int* __restrict__ gcur,
    const int* __restrict__ gbase, int* __restrict__ rowp, float* __restrict__ dinv,
    int* __restrict__ csr, int Nn) {
  __shared__ int cnt[512];
  __shared__ int scn[512];
  const int b = blockIdx.x;
  const int n0 = b << BSH;
  const int tid = threadIdx.x;
  cnt[tid] = 0;
  __syncthreads();
  int tot = gcur[b];
  if (tot > BCAP) tot = BCAP;
  for (int i = tid; i < tot; i += 512) {
    int2 pr = pairs[(size_t)b * BCAP + i];
    atomicAdd(&cnt[pr.y - n0], 1);
  }
  __syncthreads();
  int myc = cnt[tid];
  scn[tid] = myc;
  __syncthreads();
  for (int s = 1; s < 512; s <<= 1) {
    int t = (tid >= s) ? scn[tid - s] : 0;
    __syncthreads();
    scn[tid] += t;
    __syncthreads();
  }
  const int node = n0 + tid;
  const int start = gbase[b] + scn[tid] - myc;
  if (node < Nn) {
    rowp[node] = start;
    dinv[node] = rsqrtf((float)(myc + 1));  // +1 self loop
    if (node == Nn - 1) rowp[Nn] = gbase[b] + scn[tid];
  }
  cnt[tid] = start;  // reuse as cursor
  __syncthreads();
  for (int i = tid; i < tot; i += 512) {
    int2 pr = pairs[(size_t)b * BCAP + i];
    int p = atomicAdd(&cnt[pr.y - n0], 1);
    csr[p] = pr.x;
  }
}

// ---------------- bf16 pull-SpMM (wave-per-node, 16-deep batch, scalar indices) ----------------
template <int W, bool SRCF, bool DSTF>
__global__ __launch_bounds__(256) void spmm_kernel(
    const void* __restrict__ Hb, void* __restrict__ Gb,
    const int* __restrict__ rowp, const int* __restrict__ csr,
    const float* __restrict__ dinv, const u16* __restrict__ bias,
    int relu, int Nn, int src_stride, long long src_coloff,
    int dst_stride, long long dst_coloff, const int* __restrict__ flags) {
  constexpr int VPL = (W >= 64) ? (W / 64) : 1;
  constexpr int B = 16;
  const int lane = threadIdx.x & 63;
  const int node = __builtin_amdgcn_readfirstlane(blockIdx.x * 4 + (threadIdx.x >> 6));
  if (node >= Nn) return;
  const bool act = (W >= 64) || (lane < W);
  const int off = (W >= 64) ? lane * VPL : lane;
  int sf32 = 0, of32 = 0;
  if (SRCF) sf32 = flags[1];
  if (DSTF) of32 = flags[1];
  const u16* Hs = (const u16*)Hb;
  float acc[VPL];
#pragma unroll
  for (int j = 0; j < VPL; ++j) acc[j] = 0.0f;

  auto srcidx = [&](int s) -> size_t {
    return (size_t)src_coloff + (size_t)s * src_stride + off;
  };
  auto accum_row = [&](int s, float w) {
    if (!act) return;
    size_t idx = srcidx(s);
    if constexpr (W == 256) {
      int2 v = *(const int2*)(Hs + idx);
      accum_d(acc, 0, (u32)v.x, w);
      accum_d(acc, 2, (u32)v.y, w);
    } else {
      float val = (SRCF && sf32) ? ((const float*)Hb)[idx] : bf2f(Hs[idx]);
      acc[0] += w * val;
    }
  };

  const int e1 = rowp[node + 1];
  int e = rowp[node];

  for (; e + B <= e1; e += B) {
    int s[B];
#pragma unroll
    for (int j = 0; j < B; ++j) s[j] = csr[e + j];
    float wv[B];
#pragma unroll
    for (int j = 0; j < B; ++j) wv[j] = dinv[s[j]];
    if constexpr (W == 256) {
      int2 v[B];
#pragma unroll
      for (int j = 0; j < B; ++j) v[j] = *(const int2*)(Hs + srcidx(s[j]));
      if (act) {
#pragma unroll
        for (int j = 0; j < B; ++j) {
          accum_d(acc, 0, (u32)v[j].x, wv[j]);
          accum_d(acc, 2, (u32)v[j].y, wv[j]);
        }
      }
    } else {
      float v[B];
#pragma unroll
      for (int j = 0; j < B; ++j) {
        size_t idx = srcidx(s[j]);
        v[j] = (SRCF && sf32) ? ((const float*)Hb)[idx] : bf2f(Hs[idx]);
      }
      if (act) {
#pragma unroll
        for (int j = 0; j < B; ++j) acc[0] += wv[j] * v[j];
      }
    }
  }
  for (; e < e1; ++e) {
    int s = csr[e];
    accum_row(s, dinv[s]);
  }
  const float wi = dinv[node];
  accum_row(node, wi);
  if (!act) return;

  float vals[VPL];
#pragma unroll
  for (int j = 0; j < VPL; ++j) {
    float v = acc[j] * wi;
    if (bias) v += bf2f(bias[off + j]);
    if (relu) v = fmaxf(v, 0.0f);
    vals[j] = v;
  }
  size_t didx = (size_t)dst_coloff + (size_t)node * dst_stride + off;
  if constexpr (W == 256) {
    u32 d0 = (u32)f2bf(vals[0]) | ((u32)f2bf(vals[1]) << 16);
    u32 d1 = (u32)f2bf(vals[2]) | ((u32)f2bf(vals[3]) << 16);
    *(int2*)((u16*)Gb + didx) = make_int2((int)d0, (int)d1);
  } else {
    if (DSTF && of32) ((float*)Gb)[didx] = vals[0];
    else ((u16*)Gb)[didx] = f2bf(vals[0]);
  }
}

// ---------------- fp8 pull-SpMM (W=256 or 1024), packed f32x2 accumulate ----------------
// Gout[(node-n0)*dst_stride + 0:W] = dinv[node]*(sum dinv[s]*Hq[s] + dinv[node]*Hq[node])
template <int W>
__global__ __launch_bounds__(256) void spmm_fp8_kernel(
    const u8* __restrict__ Hq, u16* __restrict__ Gout,
    const int* __restrict__ rowp, const int* __restrict__ csr,
    const float* __restrict__ dinv, int n0, int n1, int dst_stride) {
  constexpr int BPL = W / 64;           // bytes (== cols) per lane: 4 or 16
  constexpr int ND = BPL / 4;           // dwords per lane: 1 or 4
  constexpr int B = (W == 1024) ? 8 : 16;
  const int lane = threadIdx.x & 63;
  const int node = __builtin_amdgcn_readfirstlane(n0 + blockIdx.x * 4 + (threadIdx.x >> 6));
  if (node >= n1) return;
  const int off = lane * BPL;
  f32x2 acc[2 * ND] = {};

  auto dec = [&](const u32* d, float w) {
    f32x2 w2 = {w, w};
#pragma unroll
    for (int q = 0; q < ND; ++q) {
      f32x2 a = __builtin_amdgcn_cvt_pk_f32_fp8((int)d[q], false);
      f32x2 b = __builtin_amdgcn_cvt_pk_f32_fp8((int)d[q], true);
      acc[2 * q] += w2 * a;
      acc[2 * q + 1] += w2 * b;
    }
  };

  const int e1r = rowp[node + 1];
  int e = rowp[node];
  for (; e + B <= e1r; e += B) {
    int s[B];
#pragma unroll
    for (int j = 0; j < B; ++j) s[j] = csr[e + j];
    float wv[B];
#pragma unroll
    for (int j = 0; j < B; ++j) wv[j] = dinv[s[j]];
    u32 v[B][ND];
#pragma unroll
    for (int j = 0; j < B; ++j) {
      const u8* p = Hq + (size_t)s[j] * W + off;
      if constexpr (ND == 4) *(int4*)&v[j][0] = *(const int4*)p;
      else v[j][0] = *(const u32*)p;
    }
#pragma unroll
    for (int j = 0; j < B; ++j) dec(v[j], wv[j]);
  }
  for (; e < e1r; ++e) {
    int s = csr[e];
    u32 v[ND];
    const u8* p = Hq + (size_t)s * W + off;
    if constexpr (ND == 4) *(int4*)&v[0] = *(const int4*)p;
    else v[0] = *(const u32*)p;
    dec(v, dinv[s]);
  }
  const float wi = dinv[node];
  {
    u32 v[ND];
    const u8* p = Hq + (size_t)node * W + off;
    if constexpr (ND == 4) *(int4*)&v[0] = *(const int4*)p;
    else v[0] = *(const u32*)p;
    dec(v, wi);
  }

  // acc order per dword q: a={c0,c1}, b={c2,c3}
  u32 d[2 * ND];
#pragma unroll
  for (int k = 0; k < 2 * ND; ++k) {
    float v0 = acc[k].x * wi, v1 = acc[k].y * wi;
    d[k] = (u32)f2bf(v0) | ((u32)f2bf(v1) << 16);
  }
  u16* gp = Gout + (size_t)(node - n0) * dst_stride + off;
  if constexpr (ND == 4) {
    ((int4*)gp)[0] = make_int4((int)d[0], (int)d[1], (int)d[2], (int)d[3]);
    ((int4*)gp)[1] = make_int4((int)d[4], (int)d[5], (int)d[6], (int)d[7]);
  } else {
    *(int2*)gp = make_int2((int)d[0], (int)d[1]);
  }
}

// ---------------- fast bf16 MFMA GEMM (m97 structure): C = A @ Bt^T ----------------
__global__ __launch_bounds__(256) void gemm_fast_kernel(
    const u16* __restrict__ A, int lda, const u16* __restrict__ Bt,
    u16* __restrict__ C, int ldc, const u16* __restrict__ bias,
    int M, int N, int K, int relu, int fp8out) {
  __shared__ __align__(16) u16 sA[128 * 64];
  __shared__ __align__(16) u16 sB[128 * 64];
  const int tid = threadIdx.x;
  const int lane = tid & 63;
  const int wave = __builtin_amdgcn_readfirstlane(tid >> 6);
  const int m0 = blockIdx.y * 128, n0 = blockIdx.x * 128;
  const int wm = (wave & 1) * 64, wn = (wave >> 1) * 64;
  const int lr = lane & 15, lq = lane >> 4;
  const int lrow = lane >> 3;
  const int lcol = (lane & 7) * 8;
  f32x4 acc[4][4] = {};

  for (int kb = 0; kb < K; kb += 64) {
#pragma unroll
    for (int it = 0; it < 4; ++it) {
      const int rbase = (it * 4 + wave) * 8;
      int gm = m0 + rbase + lrow;
      if (gm >= M) gm = M - 1;
      __builtin_amdgcn_global_load_lds(GLB_PTR(A + (size_t)gm * lda + kb + lcol),
                                       LDS_PTR(sA + rbase * 64), 16, 0, 0);
      const int gn = n0 + rbase + lrow;
      __builtin_amdgcn_global_load_lds(GLB_PTR(Bt + (size_t)gn * K + kb + lcol),
                                       LDS_PTR(sB + rbase * 64), 16, 0, 0);
    }
    __syncthreads();
#pragma unroll
    for (int ks = 0; ks < 2; ++ks) {
      bf16x8 af[4], bfr[4];
#pragma unroll
      for (int i = 0; i < 4; ++i)
        af[i] = *(const bf16x8*)(sA + (wm + i * 16 + lr) * 64 + ks * 32 + lq * 8);
#pragma unroll
      for (int i = 0; i < 4; ++i)
        bfr[i] = *(const bf16x8*)(sB + (wn + i * 16 + lr) * 64 + ks * 32 + lq * 8);
#pragma unroll
      for (int im = 0; im < 4; ++im)
#pragma unroll
        for (int in = 0; in < 4; ++in)
          acc[im][in] = __builtin_amdgcn_mfma_f32_16x16x32_bf16(af[im], bfr[in], acc[im][in], 0, 0, 0);
    }
    __syncthreads();
  }
#pragma unroll
  for (int im = 0; im < 4; ++im) {
#pragma unroll
    for (int in = 0; in < 4; ++in) {
      int col = n0 + wn + in * 16 + lr;
      float bv = bias ? bf2f(bias[col]) : 0.0f;
#pragma unroll
      for (int r = 0; r < 4; ++r) {
        int row = m0 + wm + im * 16 + lq * 4 + r;
        if (row < M) {
          float v = acc[im][in][r] + bv;
          if (relu) v = fmaxf(v, 0.0f);
          if (fp8out) {
            int pk = __builtin_amdgcn_cvt_pk_fp8_f32(v, v, 0, false);
            ((u8*)C)[(size_t)row * ldc + col] = (u8)(pk & 0xff);
          } else {
            C[(size_t)row * ldc + col] = f2bf(v);
          }
        }
      }
    }
  }
}

// ---------------- small/edge GEMM (padded-LDS, any K/N) ----------------
#define LP 72
__global__ __launch_bounds__(256) void gemm_small_kernel(
    const u16* __restrict__ A, int lda, const u16* __restrict__ Bt,
    u16* __restrict__ C, int ldc, const u16* __restrict__ bias,
    int M, int N, int K, int relu, int fp8out) {
  __shared__ __align__(16) u16 sA[128 * LP];
  __shared__ __align__(16) u16 sB[128 * LP];
  const int tid = threadIdx.x;
  const int lane = tid & 63, wave = tid >> 6;
  const int m0 = blockIdx.y * 128, n0 = blockIdx.x * 128;
  const int wm = (wave & 1) * 64, wn = (wave >> 1) * 64;
  const int lr = lane & 15;
  const int lq = lane >> 4;
  f32x4 acc[4][4] = {};

  for (int kb = 0; kb < K; kb += 64) {
#pragma unroll
    for (int it = 0; it < 4; ++it) {
      int linear = it * 2048 + tid * 8;
      int row = linear >> 6, kc = linear & 63;
      int gm = m0 + row, gk = kb + kc;
      int4 v = make_int4(0, 0, 0, 0);
      if (gm < M && gk < K) v = *(const int4*)(A + (size_t)gm * lda + gk);
      *(int4*)(sA + row * LP + kc) = v;
    }
#pragma unroll
    for (int it = 0; it < 4; ++it) {
      int linear = it * 2048 + tid * 8;
      int row = linear >> 6, kc = linear & 63;
      int gn = n0 + row, gk = kb + kc;
      int4 v = make_int4(0, 0, 0, 0);
      if (gn < N && gk < K) v = *(const int4*)(Bt + (size_t)gn * K + gk);
      *(int4*)(sB + row * LP + kc) = v;
    }
    __syncthreads();
#pragma unroll
    for (int ks = 0; ks < 2; ++ks) {
      bf16x8 af[4], bfr[4];
#pragma unroll
      for (int i = 0; i < 4; ++i)
        af[i] = *(const bf16x8*)(sA + (wm + i * 16 + lr) * LP + ks * 32 + lq * 8);
#pragma unroll
      for (int i = 0; i < 4; ++i)
        bfr[i] = *(const bf16x8*)(sB + (wn + i * 16 + lr) * LP + ks * 32 + lq * 8);
#pragma unroll
      for (int im = 0; im < 4; ++im)
#pragma unroll
        for (int in = 0; in < 4; ++in)
          acc[im][in] = __builtin_amdgcn_mfma_f32_16x16x32_bf16(af[im], bfr[in], acc[im][in], 0, 0, 0);
    }
    __syncthreads();
  }
#pragma unroll
  for (int im = 0; im < 4; ++im) {
#pragma unroll
    for (int in = 0; in < 4; ++in) {
      int col = n0 + wn + in * 16 + lr;
      if (col >= N) continue;
      float bv = bias ? bf2f(bias[col]) : 0.0f;
#pragma unroll
      for (int r = 0; r < 4; ++r) {
        int row = m0 + wm + im * 16 + lq * 4 + r;
        if (row < M) {
          float v = acc[im][in][r] + bv;
          if (relu) v = fmaxf(v, 0.0f);
          if (fp8out) {
            int pk = __builtin_amdgcn_cvt_pk_fp8_f32(v, v, 0, false);
            ((u8*)C)[(size_t)row * ldc + col] = (u8)(pk & 0xff);
          } else {
            C[(size_t)row * ldc + col] = f2bf(v);
          }
        }
      }
    }
  }
}

extern "C" void kernel_launch(void* const* d_in, const int* in_sizes, int n_in,
                              void* d_out, int out_size, void* d_ws, size_t ws_size,
                              hipStream_t stream) {
  const u16* x  = (const u16*)d_in[0];
  const int* ei = (const int*)d_in[1];

  const int Nn = in_sizes[0] / 32;   // 100000
  const int E  = in_sizes[1] / 2;    // 3200000
  const int CH = (Nn + 7) / 8;       // 12500
  const int NR = (Nn + CH - 1) / CH; // 8
  const int NB = (Nn + (1 << BSH) - 1) >> BSH;  // 196 buckets

  char* w = (char*)d_ws;
  size_t off = 0;
  auto alloc = [&](size_t bytes) -> void* {
    void* p = w + off;
    off = (off + bytes + 255) & ~(size_t)255;
    return p;
  };
  int*   flags  = (int*)alloc(256);
  int*   gcur   = (int*)alloc(1024);
  int*   gbase  = (int*)alloc(1024);
  int*   rowp   = (int*)alloc((size_t)(Nn + 1) * 4);
  float* dinv   = (float*)alloc((size_t)Nn * 4);
  int*   csr    = (int*)alloc((size_t)E * 4);
  u16*   Wt1    = (u16*)alloc((size_t)32 * 256 * 2);
  u16*   Wt2    = (u16*)alloc((size_t)256 * 1024 * 2);
  u16*   Wt3    = (u16*)alloc((size_t)1024 * 1024 * 2);
  u16*   Wt4    = (u16*)alloc((size_t)1024 * 256 * 2);
  u16*   Wt5    = (u16*)alloc((size_t)256 * 6 * 2);
  u16*   bc1    = (u16*)alloc(256 * 2);
  u16*   bc2    = (u16*)alloc(1024 * 2);
  u16*   bc3    = (u16*)alloc(1024 * 2);
  u16*   bc4    = (u16*)alloc(256 * 2);
  u16*   bc5    = (u16*)alloc(6 * 2);
  size_t selems = (size_t)CH * 1024;
  u16*   S      = (u16*)alloc(selems * 2);             // 25.6 MB staging
  u16*   H      = (u16*)alloc((size_t)Nn * 1024 * 2);  // 204.8 MB main
  const size_t required = off;
  (void)n_in;

  if (ws_size < required) {
    if (ws_size >= 4096) {
      detect_x_kernel<<<1, 256, 0, stream>>>(x, flags);
      zero_out_kernel<<<(out_size + 255) / 256, 256, 0, stream>>>(d_out, out_size, flags);
    }
    return;
  }

  // H sub-regions (u16 element offsets):
  //   h2q : fp8  u16 [0, Nn*512)          (Nn x 1024 fp8)
  //   g2/t4:     u16 [Nn*512, Nn*768)     (g2 dead after W2 -> t4 reuses)
  //   h1q : fp8  u16 [Nn*768, Nn*896)     (Nn x 256 fp8; dead after L2 spmm)
  //   h3R/h4:    u16 [Nn*768, Nn*1024)    (reuses h1q region after it dies)
  u8*  h2q = (u8*)H;
  u16* g2  = H + (size_t)Nn * 512;
  u16* t4  = H + (size_t)Nn * 512;
  u8*  h1q = (u8*)(H + (size_t)Nn * 768);
  u16* h3R = H + (size_t)Nn * 768;
  u16* h4  = H + (size_t)Nn * 768;

  // pair scratch overlaid on H (dead until CSR build completes)
  int2* pairs = (int2*)H;

  // ---- detection + bucketed CSR build ----
  detect_edge_kernel<<<1, 256, 0, stream>>>(ei, flags);
  detect_x_kernel<<<1, 256, 0, stream>>>(x, flags);
  zero_kernel<<<1, 256, 0, stream>>>(gcur, 256);
  bin_kernel<<<1024, 256, 0, stream>>>(ei, gcur, pairs, E, Nn, flags, 1024);
  bucket_scan_kernel<<<1, 256, 0, stream>>>(gcur, gbase, NB);
  bucket_finalize_kernel<<<NB, 512, 0, stream>>>(pairs, gcur, gbase, rowp, dinv, csr, Nn);

  // ---- weights/biases -> bf16 [N,K] ----
  convert_w_kernel<<<(32 * 256 + 255) / 256, 256, 0, stream>>>(d_in[2], Wt1, 32, 256, 8, flags);
  convert_w_kernel<<<1, 256, 0, stream>>>(d_in[3], bc1, 1, 256, 8, flags);
  convert_w_kernel<<<(256 * 1024 + 255) / 256, 256, 0, stream>>>(d_in[4], Wt2, 256, 1024, 10, flags);
  convert_w_kernel<<<4, 256, 0, stream>>>(d_in[5], bc2, 1, 1024, 10, flags);
  convert_w_kernel<<<(1024 * 1024 + 255) / 256, 256, 0, stream>>>(d_in[6], Wt3, 1024, 1024, 10, flags);
  convert_w_kernel<<<4, 256, 0, stream>>>(d_in[7], bc3, 1, 1024, 10, flags);
  convert_w_kernel<<<(1024 * 256 + 255) / 256, 256, 0, stream>>>(d_in[8], Wt4, 1024, 256, 8, flags);
  convert_w_kernel<<<1, 256, 0, stream>>>(d_in[9], bc4, 1, 256, 8, flags);
  convert_w_kernel<<<(256 * 6 + 255) / 256, 256, 0, stream>>>(d_in[10], Wt5, 256, 6, -1, flags);
  convert_w_kernel<<<1, 256, 0, stream>>>(d_in[11], bc5, 1, 6, -1, flags);

  const int sg = (Nn + 3) / 4;
  const int mb = (Nn + 127) / 128;

  // L1: g1 = Â x -> S (Nn x 32); h1 = relu(g1@W1+b1) -> fp8 h1q (Nn x 256)
  spmm_kernel<32, true, false><<<sg, 256, 0, stream>>>(x, S, rowp, csr, dinv, nullptr, 0, Nn,
                                                       32, 0, 32, 0, flags);
  gemm_small_kernel<<<dim3(2, mb), 256, 0, stream>>>(S, 32, Wt1, (u16*)h1q, 256, bc1,
                                                     Nn, 256, 32, 1, 1);

  // L2: g2 = Â h1q (fp8 gather, W=256) -> g2; h2 = relu(g2@W2+b2) -> fp8 h2q
  spmm_fp8_kernel<256><<<sg, 256, 0, stream>>>(h1q, g2, rowp, csr, dinv, 0, Nn, 256);
  gemm_fast_kernel<<<dim3(8, mb), 256, 0, stream>>>(g2, 256, Wt2, (u16*)h2q, 1024, bc2,
                                                    Nn, 1024, 256, 1, 1);

  // L3+L4a per row-chunk: g3_R = Â h2q (fp8, W=1024) -> S;
  //   h3_R = relu(g3_R@W3+b3) -> h3R; t4_R = h3_R@W4 -> t4[R]
  for (int R = 0; R < NR; ++R) {
    int n0 = R * CH;
    int n1 = n0 + CH < Nn ? n0 + CH : Nn;
    int MR = n1 - n0;
    int mbr = (MR + 127) / 128;
    spmm_fp8_kernel<1024><<<(MR + 3) / 4, 256, 0, stream>>>(h2q, S, rowp, csr, dinv, n0, n1, 1024);
    gemm_fast_kernel<<<dim3(8, mbr), 256, 0, stream>>>(S, 1024, Wt3, h3R, 1024, bc3,
                                                       MR, 1024, 1024, 1, 0);
    gemm_fast_kernel<<<dim3(2, mbr), 256, 0, stream>>>(h3R, 1024, Wt4, t4 + (size_t)n0 * 256, 256,
                                                       nullptr, MR, 256, 1024, 0, 0);
  }

  // L4b: h4 = relu(Â t4 + b4) -> h4 region (bf16 gather, W=256)
  spmm_kernel<256, false, false><<<sg, 256, 0, stream>>>(
      H, H, rowp, csr, dinv, bc4, 1, Nn, 256, (long long)Nn * 512, 256, (long long)Nn * 768,
      flags);

  // L5: t5 = h4@W5 -> S (Nn x 6); out = Â t5 + b5
  gemm_small_kernel<<<dim3(1, mb), 256, 0, stream>>>(h4, 256, Wt5, S, 6, nullptr,
                                                     Nn, 6, 256, 0, 0);
  spmm_kernel<6, false, true><<<sg, 256, 0, stream>>>(S, d_out, rowp, csr, dinv, bc5, 0, Nn,
                                                      6, 0, 6, 0, flags);
}

// Round 10
// 2185.573 us; speedup vs baseline: 1.4137x; 1.0135x over previous
//
#include <hip/hip_runtime.h>

typedef unsigned char u8;
typedef unsigned short u16;
typedef unsigned int u32;
typedef __bf16 bf16_t;
typedef bf16_t bf16x8 __attribute__((ext_vector_type(8)));
typedef float f32x4 __attribute__((ext_vector_type(4)));
typedef float f32x2 __attribute__((ext_vector_type(2)));

#define LDS_PTR(p) ((__attribute__((address_space(3))) unsigned int*)(p))
#define GLB_PTR(p) ((const __attribute__((address_space(1))) unsigned int*)(p))

#define BSH 9                 // bucket shift: 512 nodes per bucket
#define BCAP 32768            // pair capacity per bucket

static __device__ __forceinline__ float bf2f(u16 h) {
  u32 u = ((u32)h) << 16;
  return __builtin_bit_cast(float, u);
}
static __device__ __forceinline__ u16 f2bf(float f) {
  u32 u = __builtin_bit_cast(u32, f);
  u += 0x7fffu + ((u >> 16) & 1u);
  return (u16)(u >> 16);
}
static __device__ __forceinline__ void accum_d(float* acc, int j, u32 d, float w) {
  float lo = __builtin_bit_cast(float, d << 16);
  float hi = __builtin_bit_cast(float, d & 0xffff0000u);
  acc[j] += w * lo;
  acc[j + 1] += w * hi;
}

// ---------------- detection (fused): block 0 -> edge dtype, block 1 -> float dtype ----------------
__global__ void detect_kernel(const int* __restrict__ ei, const u16* __restrict__ x,
                              int* __restrict__ flags) {
  __shared__ int cnt;
  if (threadIdx.x == 0) cnt = 0;
  __syncthreads();
  if (blockIdx.x == 0) {
    if (ei[1 + 2 * threadIdx.x] != 0) atomicAdd(&cnt, 1);
    __syncthreads();
    if (threadIdx.x == 0) flags[0] = (cnt == 0) ? 1 : 0;
  } else {
    u32 u = x[threadIdx.x];
    u32 e = (u >> 7) & 0xFF;
    if (e >= 0x60 && e <= 0x83) atomicAdd(&cnt, 1);
    __syncthreads();
    if (threadIdx.x == 0) flags[1] = (cnt >= 240) ? 0 : 1;
  }
}

static __device__ __forceinline__ int eidx(const void* ei, size_t i, int m) {
  return m ? (int)((const long long*)ei)[i] : ((const int*)ei)[i];
}

// ---------------- utility ----------------
__global__ void zero_kernel(int* __restrict__ p, int n) {
  int i = blockIdx.x * 256 + threadIdx.x;
  if (i < n) p[i] = 0;
}

__global__ void zero_out_kernel(void* __restrict__ out, int n, const int* __restrict__ flags) {
  int i = blockIdx.x * 256 + threadIdx.x;
  if (i < n) {
    if (flags[1]) ((float*)out)[i] = 0.0f;
    else ((u16*)out)[i] = 0;
  }
}

// fused transpose+convert of all 10 weight/bias tensors
struct CvtArgs {
  const void* src[10];
  u16* dst[10];
  int K[10];
  int N[10];
  int start[11];
};
__global__ void convert_all_kernel(CvtArgs a, const int* __restrict__ flags) {
  int idx = blockIdx.x * 256 + threadIdx.x;
  int f32 = flags[1];
#pragma unroll
  for (int t = 0; t < 10; ++t) {
    if (idx >= a.start[t] && idx < a.start[t + 1]) {
      int local = idx - a.start[t];
      int K = a.K[t], N = a.N[t];
      int k = local / N, n = local - k * N;
      float v = f32 ? ((const float*)a.src[t])[local] : bf2f(((const u16*)a.src[t])[local]);
      a.dst[t][(size_t)n * K + k] = f2bf(v);
    }
  }
}

// ---------------- bucketed CSR build ----------------
__global__ __launch_bounds__(256) void bin_kernel(const void* __restrict__ ei,
                                                  int* __restrict__ gcur,
                                                  int2* __restrict__ pairs, int E, int Nn,
                                                  const int* __restrict__ flags, int nblk) {
  __shared__ int h[256];
  __shared__ int base[256];
  const int m = flags[0];
  const int nb = (Nn + (1 << BSH) - 1) >> BSH;
  const int per = (E + nblk - 1) / nblk;
  const int e0 = blockIdx.x * per;
  const int e1 = (e0 + per < E) ? e0 + per : E;
  for (int i = threadIdx.x; i < nb; i += 256) h[i] = 0;
  __syncthreads();
  for (int e = e0 + threadIdx.x; e < e1; e += 256) {
    int d = eidx(ei, (size_t)E + e, m);
    if ((u32)d < (u32)Nn) atomicAdd(&h[d >> BSH], 1);
  }
  __syncthreads();
  for (int i = threadIdx.x; i < nb; i += 256) {
    base[i] = atomicAdd(&gcur[i], h[i]);
    h[i] = 0;
  }
  __syncthreads();
  for (int e = e0 + threadIdx.x; e < e1; e += 256) {
    int d = eidx(ei, (size_t)E + e, m);
    if ((u32)d >= (u32)Nn) continue;
    int s = eidx(ei, (size_t)e, m);
    if ((u32)s >= (u32)Nn) s = 0;
    int b = d >> BSH;
    int p = base[b] + atomicAdd(&h[b], 1);
    if (p < BCAP) pairs[(size_t)b * BCAP + p] = make_int2(s, d);
  }
}

__global__ __launch_bounds__(256) void bucket_scan_kernel(const int* __restrict__ gcur,
                                                          int* __restrict__ gbase, int NB) {
  __shared__ int sd[256];
  int tid = threadIdx.x;
  int v = (tid < NB) ? gcur[tid] : 0;
  if (v > BCAP) v = BCAP;
  sd[tid] = v;
  __syncthreads();
  for (int s = 1; s < 256; s <<= 1) {
    int t = (tid >= s) ? sd[tid - s] : 0;
    __syncthreads();
    sd[tid] += t;
    __syncthreads();
  }
  if (tid < NB) gbase[tid] = sd[tid] - v;
}

__global__ __launch_bounds__(512) void bucket_finalize_kernel(
    const int2* __restrict__ pairs, const int* __restrict__ gcur,
    const int* __restrict__ gbase, int* __restrict__ rowp, float* __restrict__ dinv,
    int* __restrict__ csr, int Nn) {
  __shared__ int cnt[512];
  __shared__ int scn[512];
  const int b = blockIdx.x;
  const int n0 = b << BSH;
  const int tid = threadIdx.x;
  cnt[tid] = 0;
  __syncthreads();
  int tot = gcur[b];
  if (tot > BCAP) tot = BCAP;
  for (int i = tid; i < tot; i += 512) {
    int2 pr = pairs[(size_t)b * BCAP + i];
    atomicAdd(&cnt[pr.y - n0], 1);
  }
  __syncthreads();
  int myc = cnt[tid];
  scn[tid] = myc;
  __syncthreads();
  for (int s = 1; s < 512; s <<= 1) {
    int t = (tid >= s) ? scn[tid - s] : 0;
    __syncthreads();
    scn[tid] += t;
    __syncthreads();
  }
  const int node = n0 + tid;
  const int start = gbase[b] + scn[tid] - myc;
  if (node < Nn) {
    rowp[node] = start;
    dinv[node] = rsqrtf((float)(myc + 1));  // +1 self loop
    if (node == Nn - 1) rowp[Nn] = gbase[b] + scn[tid];
  }
  cnt[tid] = start;  // reuse as cursor
  __syncthreads();
  for (int i = tid; i < tot; i += 512) {
    int2 pr = pairs[(size_t)b * BCAP + i];
    int p = atomicAdd(&cnt[pr.y - n0], 1);
    csr[p] = pr.x;
  }
}

// ---------------- bf16 pull-SpMM (used for W=32 input gather and W=6 output) ----------------
template <int W, bool SRCF, bool DSTF>
__global__ __launch_bounds__(256) void spmm_kernel(
    const void* __restrict__ Hb, void* __restrict__ Gb,
    const int* __restrict__ rowp, const int* __restrict__ csr,
    const float* __restrict__ dinv, const u16* __restrict__ bias,
    int relu, int Nn, int src_stride, long long src_coloff,
    int dst_stride, long long dst_coloff, const int* __restrict__ flags) {
  constexpr int B = 16;
  const int lane = threadIdx.x & 63;
  const int node = __builtin_amdgcn_readfirstlane(blockIdx.x * 4 + (threadIdx.x >> 6));
  if (node >= Nn) return;
  const bool act = lane < W;
  const int off = lane;
  int sf32 = 0, of32 = 0;
  if (SRCF) sf32 = flags[1];
  if (DSTF) of32 = flags[1];
  const u16* Hs = (const u16*)Hb;
  float acc = 0.0f;

  auto srcidx = [&](int s) -> size_t {
    return (size_t)src_coloff + (size_t)s * src_stride + off;
  };
  const int e1 = rowp[node + 1];
  int e = rowp[node];
  for (; e + B <= e1; e += B) {
    int s[B];
#pragma unroll
    for (int j = 0; j < B; ++j) s[j] = csr[e + j];
    float wv[B];
#pragma unroll
    for (int j = 0; j < B; ++j) wv[j] = dinv[s[j]];
    float v[B];
#pragma unroll
    for (int j = 0; j < B; ++j) {
      size_t idx = srcidx(s[j]);
      v[j] = act ? ((SRCF && sf32) ? ((const float*)Hb)[idx] : bf2f(Hs[idx])) : 0.0f;
    }
#pragma unroll
    for (int j = 0; j < B; ++j) acc += wv[j] * v[j];
  }
  for (; e < e1; ++e) {
    int s = csr[e];
    if (act) {
      size_t idx = srcidx(s);
      acc += dinv[s] * ((SRCF && sf32) ? ((const float*)Hb)[idx] : bf2f(Hs[idx]));
    }
  }
  const float wi = dinv[node];
  if (act) {
    size_t idx = srcidx(node);
    acc += wi * ((SRCF && sf32) ? ((const float*)Hb)[idx] : bf2f(Hs[idx]));
  }
  if (!act) return;
  float v = acc * wi;
  if (bias) v += bf2f(bias[off]);
  if (relu) v = fmaxf(v, 0.0f);
  size_t didx = (size_t)dst_coloff + (size_t)node * dst_stride + off;
  if (DSTF && of32) ((float*)Gb)[didx] = v;
  else ((u16*)Gb)[didx] = f2bf(v);
}

// ---------------- fp8 pull-SpMM (W=256 or 1024), packed f32x2 accumulate ----------------
template <int W>
__global__ __launch_bounds__(256) void spmm_fp8_kernel(
    const u8* __restrict__ Hq, u16* __restrict__ Gout,
    const int* __restrict__ rowp, const int* __restrict__ csr,
    const float* __restrict__ dinv, int n0, int n1, int dst_stride) {
  constexpr int BPL = W / 64;
  constexpr int ND = BPL / 4;
  constexpr int B = (W == 1024) ? 8 : 16;
  const int lane = threadIdx.x & 63;
  const int node = __builtin_amdgcn_readfirstlane(n0 + blockIdx.x * 4 + (threadIdx.x >> 6));
  if (node >= n1) return;
  const int off = lane * BPL;
  f32x2 acc[2 * ND] = {};

  auto dec = [&](const u32* d, float w) {
    f32x2 w2 = {w, w};
#pragma unroll
    for (int q = 0; q < ND; ++q) {
      f32x2 a = __builtin_amdgcn_cvt_pk_f32_fp8((int)d[q], false);
      f32x2 b = __builtin_amdgcn_cvt_pk_f32_fp8((int)d[q], true);
      acc[2 * q] += w2 * a;
      acc[2 * q + 1] += w2 * b;
    }
  };

  const int e1r = rowp[node + 1];
  int e = rowp[node];
  for (; e + B <= e1r; e += B) {
    int s[B];
#pragma unroll
    for (int j = 0; j < B; ++j) s[j] = csr[e + j];
    float wv[B];
#pragma unroll
    for (int j = 0; j < B; ++j) wv[j] = dinv[s[j]];
    u32 v[B][ND];
#pragma unroll
    for (int j = 0; j < B; ++j) {
      const u8* p = Hq + (size_t)s[j] * W + off;
      if constexpr (ND == 4) *(int4*)&v[j][0] = *(const int4*)p;
      else v[j][0] = *(const u32*)p;
    }
#pragma unroll
    for (int j = 0; j < B; ++j) dec(v[j], wv[j]);
  }
  for (; e < e1r; ++e) {
    int s = csr[e];
    u32 v[ND];
    const u8* p = Hq + (size_t)s * W + off;
    if constexpr (ND == 4) *(int4*)&v[0] = *(const int4*)p;
    else v[0] = *(const u32*)p;
    dec(v, dinv[s]);
  }
  const float wi = dinv[node];
  {
    u32 v[ND];
    const u8* p = Hq + (size_t)node * W + off;
    if constexpr (ND == 4) *(int4*)&v[0] = *(const int4*)p;
    else v[0] = *(const u32*)p;
    dec(v, wi);
  }

  u32 d[2 * ND];
#pragma unroll
  for (int k = 0; k < 2 * ND; ++k) {
    float v0 = acc[k].x * wi, v1 = acc[k].y * wi;
    d[k] = (u32)f2bf(v0) | ((u32)f2bf(v1) << 16);
  }
  u16* gp = Gout + (size_t)(node - n0) * dst_stride + off;
  if constexpr (ND == 4) {
    ((int4*)gp)[0] = make_int4((int)d[0], (int)d[1], (int)d[2], (int)d[3]);
    ((int4*)gp)[1] = make_int4((int)d[4], (int)d[5], (int)d[6], (int)d[7]);
  } else {
    *(int2*)gp = make_int2((int)d[0], (int)d[1]);
  }
}

// ---------------- int8 pull-SpMM (W=256, global scale), 4 cols/lane ----------------
__global__ __launch_bounds__(256) void spmm_i8_kernel(
    const u8* __restrict__ Hq, u16* __restrict__ G,
    const int* __restrict__ rowp, const int* __restrict__ csr,
    const float* __restrict__ dinv, const u32* __restrict__ maxbits,
    const u16* __restrict__ bias, int relu, int Nn, int dst_stride) {
  constexpr int B = 16;
  const int lane = threadIdx.x & 63;
  const int node = __builtin_amdgcn_readfirstlane(blockIdx.x * 4 + (threadIdx.x >> 6));
  if (node >= Nn) return;
  const int off = lane * 4;
  float mx = __builtin_bit_cast(float, *maxbits);
  float sq = mx > 0.0f ? mx * (1.0f / 127.0f) : 0.0f;
  float acc[4] = {};

  auto dec = [&](u32 d, float w) {
    acc[0] += w * (float)(int)(char)(d & 0xff);
    acc[1] += w * (float)(int)(char)((d >> 8) & 0xff);
    acc[2] += w * (float)(int)(char)((d >> 16) & 0xff);
    acc[3] += w * (float)(int)(char)(d >> 24);
  };

  const int e1 = rowp[node + 1];
  int e = rowp[node];
  for (; e + B <= e1; e += B) {
    int s[B];
#pragma unroll
    for (int j = 0; j < B; ++j) s[j] = csr[e + j];
    float wv[B];
#pragma unroll
    for (int j = 0; j < B; ++j) wv[j] = dinv[s[j]];
    u32 v[B];
#pragma unroll
    for (int j = 0; j < B; ++j) v[j] = *(const u32*)(Hq + (size_t)s[j] * 256 + off);
#pragma unroll
    for (int j = 0; j < B; ++j) dec(v[j], wv[j]);
  }
  for (; e < e1; ++e) {
    int s = csr[e];
    dec(*(const u32*)(Hq + (size_t)s * 256 + off), dinv[s]);
  }
  const float wi = dinv[node];
  dec(*(const u32*)(Hq + (size_t)node * 256 + off), wi);

  float vals[4];
#pragma unroll
  for (int k = 0; k < 4; ++k) {
    float v = acc[k] * wi * sq;
    if (bias) v += bf2f(bias[off + k]);
    if (relu) v = fmaxf(v, 0.0f);
    vals[k] = v;
  }
  u32 d0 = (u32)f2bf(vals[0]) | ((u32)f2bf(vals[1]) << 16);
  u32 d1 = (u32)f2bf(vals[2]) | ((u32)f2bf(vals[3]) << 16);
  *(int2*)(G + (size_t)node * dst_stride + off) = make_int2((int)d0, (int)d1);
}

// ---------------- t4 bf16 -> int8 quantize (global scale from maxbits) ----------------
__global__ void quant_kernel(const u16* __restrict__ t4, u8* __restrict__ t4q,
                             const u32* __restrict__ maxbits, int n4) {
  int i = blockIdx.x * 256 + threadIdx.x;
  if (i >= n4) return;
  float mx = __builtin_bit_cast(float, *maxbits);
  float inv = mx > 0.0f ? 127.0f / mx : 0.0f;
  int2 v = ((const int2*)t4)[i];
  float f0 = bf2f((u16)(v.x & 0xffff)), f1 = bf2f((u16)((u32)v.x >> 16));
  float f2 = bf2f((u16)(v.y & 0xffff)), f3 = bf2f((u16)((u32)v.y >> 16));
  int q0 = (int)rintf(f0 * inv), q1 = (int)rintf(f1 * inv);
  int q2 = (int)rintf(f2 * inv), q3 = (int)rintf(f3 * inv);
  q0 = min(127, max(-127, q0)); q1 = min(127, max(-127, q1));
  q2 = min(127, max(-127, q2)); q3 = min(127, max(-127, q3));
  ((u32*)t4q)[i] = (u32)(q0 & 0xff) | ((u32)(q1 & 0xff) << 8) |
                   ((u32)(q2 & 0xff) << 16) | ((u32)(q3 & 0xff) << 24);
}

// ---------------- fast bf16 MFMA GEMM (m97 structure): C = A @ Bt^T ----------------
__global__ __launch_bounds__(256) void gemm_fast_kernel(
    const u16* __restrict__ A, int lda, const u16* __restrict__ Bt,
    u16* __restrict__ C, int ldc, const u16* __restrict__ bias,
    int M, int N, int K, int relu, int fp8out, u32* __restrict__ maxout) {
  __shared__ __align__(16) u16 sA[128 * 64];
  __shared__ __align__(16) u16 sB[128 * 64];
  const int tid = threadIdx.x;
  const int lane = tid & 63;
  const int wave = __builtin_amdgcn_readfirstlane(tid >> 6);
  const int m0 = blockIdx.y * 128, n0 = blockIdx.x * 128;
  const int wm = (wave & 1) * 64, wn = (wave >> 1) * 64;
  const int lr = lane & 15, lq = lane >> 4;
  const int lrow = lane >> 3;
  const int lcol = (lane & 7) * 8;
  f32x4 acc[4][4] = {};

  for (int kb = 0; kb < K; kb += 64) {
#pragma unroll
    for (int it = 0; it < 4; ++it) {
      const int rbase = (it * 4 + wave) * 8;
      int gm = m0 + rbase + lrow;
      if (gm >= M) gm = M - 1;
      __builtin_amdgcn_global_load_lds(GLB_PTR(A + (size_t)gm * lda + kb + lcol),
                                       LDS_PTR(sA + rbase * 64), 16, 0, 0);
      const int gn = n0 + rbase + lrow;
      __builtin_amdgcn_global_load_lds(GLB_PTR(Bt + (size_t)gn * K + kb + lcol),
                                       LDS_PTR(sB + rbase * 64), 16, 0, 0);
    }
    __syncthreads();
#pragma unroll
    for (int ks = 0; ks < 2; ++ks) {
      bf16x8 af[4], bfr[4];
#pragma unroll
      for (int i = 0; i < 4; ++i)
        af[i] = *(const bf16x8*)(sA + (wm + i * 16 + lr) * 64 + ks * 32 + lq * 8);
#pragma unroll
      for (int i = 0; i < 4; ++i)
        bfr[i] = *(const bf16x8*)(sB + (wn + i * 16 + lr) * 64 + ks * 32 + lq * 8);
#pragma unroll
      for (int im = 0; im < 4; ++im)
#pragma unroll
        for (int in = 0; in < 4; ++in)
          acc[im][in] = __builtin_amdgcn_mfma_f32_16x16x32_bf16(af[im], bfr[in], acc[im][in], 0, 0, 0);
    }
    __syncthreads();
  }
  u32 mymax = 0;
#pragma unroll
  for (int im = 0; im < 4; ++im) {
#pragma unroll
    for (int in = 0; in < 4; ++in) {
      int col = n0 + wn + in * 16 + lr;
      float bv = bias ? bf2f(bias[col]) : 0.0f;
#pragma unroll
      for (int r = 0; r < 4; ++r) {
        int row = m0 + wm + im * 16 + lq * 4 + r;
        if (row < M) {
          float v = acc[im][in][r] + bv;
          if (relu) v = fmaxf(v, 0.0f);
          if (maxout) {
            u32 ab = __builtin_bit_cast(u32, v) & 0x7fffffffu;
            mymax = mymax > ab ? mymax : ab;
          }
          if (fp8out) {
            int pk = __builtin_amdgcn_cvt_pk_fp8_f32(v, v, 0, false);
            ((u8*)C)[(size_t)row * ldc + col] = (u8)(pk & 0xff);
          } else {
            C[(size_t)row * ldc + col] = f2bf(v);
          }
        }
      }
    }
  }
  if (maxout) {
    u32* red = (u32*)sA;
    red[tid] = mymax;
    __syncthreads();
    for (int s = 128; s > 0; s >>= 1) {
      if (tid < s) red[tid] = red[tid] > red[tid + s] ? red[tid] : red[tid + s];
      __syncthreads();
    }
    if (tid == 0) atomicMax(maxout, red[0]);
  }
}

// ---------------- small/edge GEMM (padded-LDS, any K/N) ----------------
#define LP 72
__global__ __launch_bounds__(256) void gemm_small_kernel(
    const u16* __restrict__ A, int lda, const u16* __restrict__ Bt,
    u16* __restrict__ C, int ldc, const u16* __restrict__ bias,
    int M, int N, int K, int relu, int fp8out) {
  __shared__ __align__(16) u16 sA[128 * LP];
  __shared__ __align__(16) u16 sB[128 * LP];
  const int tid = threadIdx.x;
  const int lane = tid & 63, wave = tid >> 6;
  const int m0 = blockIdx.y * 128, n0 = blockIdx.x * 128;
  const int wm = (wave & 1) * 64, wn = (wave >> 1) * 64;
  const int lr = lane & 15;
  const int lq = lane >> 4;
  f32x4 acc[4][4] = {};

  for (int kb = 0; kb < K; kb += 64) {
#pragma unroll
    for (int it = 0; it < 4; ++it) {
      int linear = it * 2048 + tid * 8;
      int row = linear >> 6, kc = linear & 63;
      int gm = m0 + row, gk = kb + kc;
      int4 v = make_int4(0, 0, 0, 0);
      if (gm < M && gk < K) v = *(const int4*)(A + (size_t)gm * lda + gk);
      *(int4*)(sA + row * LP + kc) = v;
    }
#pragma unroll
    for (int it = 0; it < 4; ++it) {
      int linear = it * 2048 + tid * 8;
      int row = linear >> 6, kc = linear & 63;
      int gn = n0 + row, gk = kb + kc;
      int4 v = make_int4(0, 0, 0, 0);
      if (gn < N && gk < K) v = *(const int4*)(Bt + (size_t)gn * K + gk);
      *(int4*)(sB + row * LP + kc) = v;
    }
    __syncthreads();
#pragma unroll
    for (int ks = 0; ks < 2; ++ks) {
      bf16x8 af[4], bfr[4];
#pragma unroll
      for (int i = 0; i < 4; ++i)
        af[i] = *(const bf16x8*)(sA + (wm + i * 16 + lr) * LP + ks * 32 + lq * 8);
#pragma unroll
      for (int i = 0; i < 4; ++i)
        bfr[i] = *(const bf16x8*)(sB + (wn + i * 16 + lr) * LP + ks * 32 + lq * 8);
#pragma unroll
      for (int im = 0; im < 4; ++im)
#pragma unroll
        for (int in = 0; in < 4; ++in)
          acc[im][in] = __builtin_amdgcn_mfma_f32_16x16x32_bf16(af[im], bfr[in], acc[im][in], 0, 0, 0);
    }
    __syncthreads();
  }
#pragma unroll
  for (int im = 0; im < 4; ++im) {
#pragma unroll
    for (int in = 0; in < 4; ++in) {
      int col = n0 + wn + in * 16 + lr;
      if (col >= N) continue;
      float bv = bias ? bf2f(bias[col]) : 0.0f;
#pragma unroll
      for (int r = 0; r < 4; ++r) {
        int row = m0 + wm + im * 16 + lq * 4 + r;
        if (row < M) {
          float v = acc[im][in][r] + bv;
          if (relu) v = fmaxf(v, 0.0f);
          if (fp8out) {
            int pk = __builtin_amdgcn_cvt_pk_fp8_f32(v, v, 0, false);
            ((u8*)C)[(size_t)row * ldc + col] = (u8)(pk & 0xff);
          } else {
            C[(size_t)row * ldc + col] = f2bf(v);
          }
        }
      }
    }
  }
}

extern "C" void kernel_launch(void* const* d_in, const int* in_sizes, int n_in,
                              void* d_out, int out_size, void* d_ws, size_t ws_size,
                              hipStream_t stream) {
  const u16* x  = (const u16*)d_in[0];
  const int* ei = (const int*)d_in[1];

  const int Nn = in_sizes[0] / 32;   // 100000
  const int E  = in_sizes[1] / 2;    // 3200000
  const int CH = (Nn + 7) / 8;       // 12500
  const int NR = (Nn + CH - 1) / CH; // 8
  const int NB = (Nn + (1 << BSH) - 1) >> BSH;  // 196 buckets

  char* w = (char*)d_ws;
  size_t off = 0;
  auto alloc = [&](size_t bytes) -> void* {
    void* p = w + off;
    off = (off + bytes + 255) & ~(size_t)255;
    return p;
  };
  int*   flags  = (int*)alloc(256);
  int*   gcur   = (int*)alloc(1024);   // gcur, gbase, tmax contiguous: one zero pass
  int*   gbase  = (int*)alloc(1024);
  u32*   tmax   = (u32*)alloc(256);
  int*   rowp   = (int*)alloc((size_t)(Nn + 1) * 4);
  float* dinv   = (float*)alloc((size_t)Nn * 4);
  int*   csr    = (int*)alloc((size_t)E * 4);
  u16*   Wt1    = (u16*)alloc((size_t)32 * 256 * 2);
  u16*   Wt2    = (u16*)alloc((size_t)256 * 1024 * 2);
  u16*   Wt3    = (u16*)alloc((size_t)1024 * 1024 * 2);
  u16*   Wt4    = (u16*)alloc((size_t)1024 * 256 * 2);
  u16*   Wt5    = (u16*)alloc((size_t)256 * 6 * 2);
  u16*   bc1    = (u16*)alloc(256 * 2);
  u16*   bc2    = (u16*)alloc(1024 * 2);
  u16*   bc3    = (u16*)alloc(1024 * 2);
  u16*   bc4    = (u16*)alloc(256 * 2);
  u16*   bc5    = (u16*)alloc(6 * 2);
  size_t selems = (size_t)CH * 1024;
  u16*   S      = (u16*)alloc(selems * 2);             // 25.6 MB staging
  u16*   H      = (u16*)alloc((size_t)Nn * 1024 * 2);  // 204.8 MB main
  const size_t required = off;
  (void)n_in;

  if (ws_size < required) {
    if (ws_size >= 4096) {
      detect_kernel<<<2, 256, 0, stream>>>(ei, x, flags);
      zero_out_kernel<<<(out_size + 255) / 256, 256, 0, stream>>>(d_out, out_size, flags);
    }
    return;
  }

  // H sub-regions (u16 element offsets):
  //   h2q : fp8  u16 [0, Nn*512)          (Nn x 1024 fp8; dead after last L3 chunk)
  //   t4q : i8   bytes [0, Nn*256)        (overlays dead h2q)
  //   g2/t4:     u16 [Nn*512, Nn*768)
  //   h1q : fp8  u16 [Nn*768, Nn*896)     (dead after L2 spmm)
  //   h3R/h4:    u16 [Nn*768, Nn*1024)
  u8*  h2q = (u8*)H;
  u8*  t4q = (u8*)H;
  u16* g2  = H + (size_t)Nn * 512;
  u16* t4  = H + (size_t)Nn * 512;
  u8*  h1q = (u8*)(H + (size_t)Nn * 768);
  u16* h3R = H + (size_t)Nn * 768;
  u16* h4  = H + (size_t)Nn * 768;

  int2* pairs = (int2*)H;  // CSR-build scratch, dead after build

  // ---- detection + bucketed CSR build ----
  detect_kernel<<<2, 256, 0, stream>>>(ei, x, flags);
  zero_kernel<<<3, 256, 0, stream>>>(gcur, 576);  // gcur + gbase + tmax
  bin_kernel<<<1024, 256, 0, stream>>>(ei, gcur, pairs, E, Nn, flags, 1024);
  bucket_scan_kernel<<<1, 256, 0, stream>>>(gcur, gbase, NB);
  bucket_finalize_kernel<<<NB, 512, 0, stream>>>(pairs, gcur, gbase, rowp, dinv, csr, Nn);

  // ---- weights/biases -> bf16 [N,K], one fused launch ----
  {
    CvtArgs a;
    const int Ks[10] = {32, 1, 256, 1, 1024, 1, 1024, 1, 256, 1};
    const int Ns[10] = {256, 256, 1024, 1024, 1024, 1024, 256, 256, 6, 6};
    u16* ds[10] = {Wt1, bc1, Wt2, bc2, Wt3, bc3, Wt4, bc4, Wt5, bc5};
    int cum = 0;
    for (int t = 0; t < 10; ++t) {
      a.src[t] = d_in[2 + t];
      a.dst[t] = ds[t];
      a.K[t] = Ks[t];
      a.N[t] = Ns[t];
      a.start[t] = cum;
      cum += Ks[t] * Ns[t];
    }
    a.start[10] = cum;
    convert_all_kernel<<<(cum + 255) / 256, 256, 0, stream>>>(a, flags);
  }

  const int sg = (Nn + 3) / 4;
  const int mb = (Nn + 127) / 128;

  // L1: g1 = Â x -> S (Nn x 32); h1 = relu(g1@W1+b1) -> fp8 h1q (Nn x 256)
  spmm_kernel<32, true, false><<<sg, 256, 0, stream>>>(x, S, rowp, csr, dinv, nullptr, 0, Nn,
                                                       32, 0, 32, 0, flags);
  gemm_small_kernel<<<dim3(2, mb), 256, 0, stream>>>(S, 32, Wt1, (u16*)h1q, 256, bc1,
                                                     Nn, 256, 32, 1, 1);

  // L2: g2 = Â h1q (fp8, W=256) -> g2; h2 = relu(g2@W2+b2) -> fp8 h2q
  spmm_fp8_kernel<256><<<sg, 256, 0, stream>>>(h1q, g2, rowp, csr, dinv, 0, Nn, 256);
  gemm_fast_kernel<<<dim3(8, mb), 256, 0, stream>>>(g2, 256, Wt2, (u16*)h2q, 1024, bc2,
                                                    Nn, 1024, 256, 1, 1, nullptr);

  // L3+L4a per row-chunk; W4 epilogue tracks global max|t4| into tmax
  for (int R = 0; R < NR; ++R) {
    int n0 = R * CH;
    int n1 = n0 + CH < Nn ? n0 + CH : Nn;
    int MR = n1 - n0;
    int mbr = (MR + 127) / 128;
    spmm_fp8_kernel<1024><<<(MR + 3) / 4, 256, 0, stream>>>(h2q, S, rowp, csr, dinv, n0, n1, 1024);
    gemm_fast_kernel<<<dim3(8, mbr), 256, 0, stream>>>(S, 1024, Wt3, h3R, 1024, bc3,
                                                       MR, 1024, 1024, 1, 0, nullptr);
    gemm_fast_kernel<<<dim3(2, mbr), 256, 0, stream>>>(h3R, 1024, Wt4, t4 + (size_t)n0 * 256, 256,
                                                       nullptr, MR, 256, 1024, 0, 0, tmax);
  }

  // quantize t4 -> int8 (global scale) into dead h2q space
  quant_kernel<<<(Nn * 64 + 255) / 256, 256, 0, stream>>>(t4, t4q, tmax, Nn * 64);

  // L4b: h4 = relu(Â t4q + b4) -> h4 (int8 gather, W=256)
  spmm_i8_kernel<<<sg, 256, 0, stream>>>(t4q, h4, rowp, csr, dinv, tmax, bc4, 1, Nn, 256);

  // L5: t5 = h4@W5 -> S (Nn x 6); out = Â t5 + b5
  gemm_small_kernel<<<dim3(1, mb), 256, 0, stream>>>(h4, 256, Wt5, S, 6, nullptr,
                                                     Nn, 6, 256, 0, 0);
  spmm_kernel<6, false, true><<<sg, 256, 0, stream>>>(S, d_out, rowp, csr, dinv, bc5, 0, Nn,
                                                      6, 0, 6, 0, flags);
}

// Round 11
// 2104.062 us; speedup vs baseline: 1.4685x; 1.0387x over previous
//
#include <hip/hip_runtime.h>

typedef unsigned char u8;
typedef unsigned short u16;
typedef unsigned int u32;
typedef __bf16 bf16_t;
typedef bf16_t bf16x8 __attribute__((ext_vector_type(8)));
typedef float f32x4 __attribute__((ext_vector_type(4)));
typedef float f32x2 __attribute__((ext_vector_type(2)));

#define LDS_PTR(p) ((__attribute__((address_space(3))) unsigned int*)(p))
#define GLB_PTR(p) ((const __attribute__((address_space(1))) unsigned int*)(p))

#define BSH 9                 // bucket shift: 512 nodes per bucket
#define BCAP 32768            // pair capacity per bucket

static __device__ __forceinline__ float bf2f(u16 h) {
  u32 u = ((u32)h) << 16;
  return __builtin_bit_cast(float, u);
}
static __device__ __forceinline__ u16 f2bf(float f) {
  u32 u = __builtin_bit_cast(u32, f);
  u += 0x7fffu + ((u >> 16) & 1u);
  return (u16)(u >> 16);
}

// ---------------- detection + scratch zeroing (fused) ----------------
__global__ void detect_kernel(const int* __restrict__ ei, const u16* __restrict__ x,
                              int* __restrict__ flags, int* __restrict__ zp, int zn) {
  __shared__ int cnt;
  if (threadIdx.x == 0) cnt = 0;
  __syncthreads();
  if (blockIdx.x == 0) {
    if (ei[1 + 2 * threadIdx.x] != 0) atomicAdd(&cnt, 1);
    __syncthreads();
    if (threadIdx.x == 0) flags[0] = (cnt == 0) ? 1 : 0;
  } else if (blockIdx.x == 1) {
    u32 u = x[threadIdx.x];
    u32 e = (u >> 7) & 0xFF;
    if (e >= 0x60 && e <= 0x83) atomicAdd(&cnt, 1);
    __syncthreads();
    if (threadIdx.x == 0) flags[1] = (cnt >= 240) ? 0 : 1;
  } else {
    for (int i = threadIdx.x; i < zn; i += 256) zp[i] = 0;
  }
}

static __device__ __forceinline__ int eidx(const void* ei, size_t i, int m) {
  return m ? (int)((const long long*)ei)[i] : ((const int*)ei)[i];
}

__global__ void zero_out_kernel(void* __restrict__ out, int n, const int* __restrict__ flags) {
  int i = blockIdx.x * 256 + threadIdx.x;
  if (i < n) {
    if (flags[1]) ((float*)out)[i] = 0.0f;
    else ((u16*)out)[i] = 0;
  }
}

// fused transpose+convert of all 10 weight/bias tensors
struct CvtArgs {
  const void* src[10];
  u16* dst[10];
  int K[10];
  int N[10];
  int start[11];
};
__global__ void convert_all_kernel(CvtArgs a, const int* __restrict__ flags) {
  int idx = blockIdx.x * 256 + threadIdx.x;
  int f32 = flags[1];
#pragma unroll
  for (int t = 0; t < 10; ++t) {
    if (idx >= a.start[t] && idx < a.start[t + 1]) {
      int local = idx - a.start[t];
      int K = a.K[t], N = a.N[t];
      int k = local / N, n = local - k * N;
      float v = f32 ? ((const float*)a.src[t])[local] : bf2f(((const u16*)a.src[t])[local]);
      a.dst[t][(size_t)n * K + k] = f2bf(v);
    }
  }
}

// ---------------- bucketed CSR build ----------------
__global__ __launch_bounds__(256) void bin_kernel(const void* __restrict__ ei,
                                                  int* __restrict__ gcur,
                                                  int2* __restrict__ pairs, int E, int Nn,
                                                  const int* __restrict__ flags, int nblk) {
  __shared__ int h[256];
  __shared__ int base[256];
  const int m = flags[0];
  const int nb = (Nn + (1 << BSH) - 1) >> BSH;
  const int per = (E + nblk - 1) / nblk;
  const int e0 = blockIdx.x * per;
  const int e1 = (e0 + per < E) ? e0 + per : E;
  for (int i = threadIdx.x; i < nb; i += 256) h[i] = 0;
  __syncthreads();
  for (int e = e0 + threadIdx.x; e < e1; e += 256) {
    int d = eidx(ei, (size_t)E + e, m);
    if ((u32)d < (u32)Nn) atomicAdd(&h[d >> BSH], 1);
  }
  __syncthreads();
  for (int i = threadIdx.x; i < nb; i += 256) {
    base[i] = atomicAdd(&gcur[i], h[i]);
    h[i] = 0;
  }
  __syncthreads();
  for (int e = e0 + threadIdx.x; e < e1; e += 256) {
    int d = eidx(ei, (size_t)E + e, m);
    if ((u32)d >= (u32)Nn) continue;
    int s = eidx(ei, (size_t)e, m);
    if ((u32)s >= (u32)Nn) s = 0;
    int b = d >> BSH;
    int p = base[b] + atomicAdd(&h[b], 1);
    if (p < BCAP) pairs[(size_t)b * BCAP + p] = make_int2(s, d);
  }
}

__global__ __launch_bounds__(256) void bucket_scan_kernel(const int* __restrict__ gcur,
                                                          int* __restrict__ gbase, int NB) {
  __shared__ int sd[256];
  int tid = threadIdx.x;
  int v = (tid < NB) ? gcur[tid] : 0;
  if (v > BCAP) v = BCAP;
  sd[tid] = v;
  __syncthreads();
  for (int s = 1; s < 256; s <<= 1) {
    int t = (tid >= s) ? sd[tid - s] : 0;
    __syncthreads();
    sd[tid] += t;
    __syncthreads();
  }
  if (tid < NB) gbase[tid] = sd[tid] - v;
}

__global__ __launch_bounds__(512) void bucket_finalize_kernel(
    const int2* __restrict__ pairs, const int* __restrict__ gcur,
    const int* __restrict__ gbase, int* __restrict__ rowp, float* __restrict__ dinv,
    int* __restrict__ csr, int Nn) {
  __shared__ int cnt[512];
  __shared__ int scn[512];
  const int b = blockIdx.x;
  const int n0 = b << BSH;
  const int tid = threadIdx.x;
  cnt[tid] = 0;
  __syncthreads();
  int tot = gcur[b];
  if (tot > BCAP) tot = BCAP;
  for (int i = tid; i < tot; i += 512) {
    int2 pr = pairs[(size_t)b * BCAP + i];
    atomicAdd(&cnt[pr.y - n0], 1);
  }
  __syncthreads();
  int myc = cnt[tid];
  scn[tid] = myc;
  __syncthreads();
  for (int s = 1; s < 512; s <<= 1) {
    int t = (tid >= s) ? scn[tid - s] : 0;
    __syncthreads();
    scn[tid] += t;
    __syncthreads();
  }
  const int node = n0 + tid;
  const int start = gbase[b] + scn[tid] - myc;
  if (node < Nn) {
    rowp[node] = start;
    dinv[node] = rsqrtf((float)(myc + 1));  // +1 self loop
    if (node == Nn - 1) rowp[Nn] = gbase[b] + scn[tid];
  }
  cnt[tid] = start;  // reuse as cursor
  __syncthreads();
  for (int i = tid; i < tot; i += 512) {
    int2 pr = pairs[(size_t)b * BCAP + i];
    int p = atomicAdd(&cnt[pr.y - n0], 1);
    csr[p] = pr.x;
  }
}

// ---------------- narrow pull-SpMM: NPW nodes/wave, G=64/NPW lanes/node, 1 col/lane ----------------
template <int NPW, int ACT, bool SRCF, bool DSTF>
__global__ __launch_bounds__(256) void spmm_narrow_kernel(
    const void* __restrict__ Hb, void* __restrict__ Gb,
    const int* __restrict__ rowp, const int* __restrict__ csr,
    const float* __restrict__ dinv, const u16* __restrict__ bias,
    int relu, int Nn, int src_stride, int dst_stride, const int* __restrict__ flags) {
  constexpr int G = 64 / NPW;
  constexpr int B = 16;
  const int lane = threadIdx.x & 63;
  const int col = lane & (G - 1);
  const int node = blockIdx.x * 4 * NPW + (threadIdx.x >> 6) * NPW + (lane / G);
  const bool anode = node < Nn;
  const bool act = anode && (col < ACT);
  int sf32 = 0, of32 = 0;
  if (SRCF) sf32 = flags[1];
  if (DSTF) of32 = flags[1];
  const u16* Hs = (const u16*)Hb;
  const float* Hf = (const float*)Hb;

  int e0 = 0, cnt = 0;
  if (anode) {
    e0 = rowp[node];
    cnt = rowp[node + 1] - e0;
  }
  float acc = 0.0f;
  for (int jb = 0; jb < cnt; jb += B) {
    int s[B];
    float wv[B];
#pragma unroll
    for (int j = 0; j < B; ++j) {
      bool val = (jb + j) < cnt;
      s[j] = val ? csr[e0 + jb + j] : node;
      wv[j] = val ? dinv[s[j]] : 0.0f;
    }
    float v[B];
#pragma unroll
    for (int j = 0; j < B; ++j) {
      size_t idx = (size_t)s[j] * src_stride + col;
      v[j] = act ? ((SRCF && sf32) ? Hf[idx] : bf2f(Hs[idx])) : 0.0f;
    }
#pragma unroll
    for (int j = 0; j < B; ++j) acc += wv[j] * v[j];
  }
  if (!act) return;
  const float wi = dinv[node];
  {
    size_t idx = (size_t)node * src_stride + col;
    acc += wi * ((SRCF && sf32) ? Hf[idx] : bf2f(Hs[idx]));
  }
  float v = acc * wi;
  if (bias) v += bf2f(bias[col]);
  if (relu) v = fmaxf(v, 0.0f);
  size_t didx = (size_t)node * dst_stride + col;
  if (DSTF && of32) ((float*)Gb)[didx] = v;
  else ((u16*)Gb)[didx] = f2bf(v);
}

// ---------------- fp8 pull-SpMM (W=256 or 1024), packed f32x2 accumulate ----------------
template <int W>
__global__ __launch_bounds__(256) void spmm_fp8_kernel(
    const u8* __restrict__ Hq, u16* __restrict__ Gout,
    const int* __restrict__ rowp, const int* __restrict__ csr,
    const float* __restrict__ dinv, int n0, int n1, int dst_stride) {
  constexpr int BPL = W / 64;
  constexpr int ND = BPL / 4;
  constexpr int B = (W == 1024) ? 8 : 16;
  const int lane = threadIdx.x & 63;
  const int node = __builtin_amdgcn_readfirstlane(n0 + blockIdx.x * 4 + (threadIdx.x >> 6));
  if (node >= n1) return;
  const int off = lane * BPL;
  f32x2 acc[2 * ND] = {};

  auto dec = [&](const u32* d, float w) {
    f32x2 w2 = {w, w};
#pragma unroll
    for (int q = 0; q < ND; ++q) {
      f32x2 a = __builtin_amdgcn_cvt_pk_f32_fp8((int)d[q], false);
      f32x2 b = __builtin_amdgcn_cvt_pk_f32_fp8((int)d[q], true);
      acc[2 * q] += w2 * a;
      acc[2 * q + 1] += w2 * b;
    }
  };

  const int e1r = rowp[node + 1];
  int e = rowp[node];
  for (; e + B <= e1r; e += B) {
    int s[B];
#pragma unroll
    for (int j = 0; j < B; ++j) s[j] = csr[e + j];
    float wv[B];
#pragma unroll
    for (int j = 0; j < B; ++j) wv[j] = dinv[s[j]];
    u32 v[B][ND];
#pragma unroll
    for (int j = 0; j < B; ++j) {
      const u8* p = Hq + (size_t)s[j] * W + off;
      if constexpr (ND == 4) *(int4*)&v[j][0] = *(const int4*)p;
      else v[j][0] = *(const u32*)p;
    }
#pragma unroll
    for (int j = 0; j < B; ++j) dec(v[j], wv[j]);
  }
  for (; e < e1r; ++e) {
    int s = csr[e];
    u32 v[ND];
    const u8* p = Hq + (size_t)s * W + off;
    if constexpr (ND == 4) *(int4*)&v[0] = *(const int4*)p;
    else v[0] = *(const u32*)p;
    dec(v, dinv[s]);
  }
  const float wi = dinv[node];
  {
    u32 v[ND];
    const u8* p = Hq + (size_t)node * W + off;
    if constexpr (ND == 4) *(int4*)&v[0] = *(const int4*)p;
    else v[0] = *(const u32*)p;
    dec(v, wi);
  }

  u32 d[2 * ND];
#pragma unroll
  for (int k = 0; k < 2 * ND; ++k) {
    float v0 = acc[k].x * wi, v1 = acc[k].y * wi;
    d[k] = (u32)f2bf(v0) | ((u32)f2bf(v1) << 16);
  }
  u16* gp = Gout + (size_t)(node - n0) * dst_stride + off;
  if constexpr (ND == 4) {
    ((int4*)gp)[0] = make_int4((int)d[0], (int)d[1], (int)d[2], (int)d[3]);
    ((int4*)gp)[1] = make_int4((int)d[4], (int)d[5], (int)d[6], (int)d[7]);
  } else {
    *(int2*)gp = make_int2((int)d[0], (int)d[1]);
  }
}

// ---------------- uint8 pull-SpMM (W=256, global scale, bias-128 encoding) ----------------
// decode via v_cvt_f32_ubyte{0..3} pattern; bias corrected once per row via wsum.
__global__ __launch_bounds__(256) void spmm_u8_kernel(
    const u8* __restrict__ Hq, u16* __restrict__ G,
    const int* __restrict__ rowp, const int* __restrict__ csr,
    const float* __restrict__ dinv, const u32* __restrict__ maxbits,
    const u16* __restrict__ bias, int relu, int Nn, int dst_stride) {
  constexpr int B = 16;
  const int lane = threadIdx.x & 63;
  const int node = __builtin_amdgcn_readfirstlane(blockIdx.x * 4 + (threadIdx.x >> 6));
  if (node >= Nn) return;
  const int off = lane * 4;
  float mx = __builtin_bit_cast(float, *maxbits);
  float sq = mx > 0.0f ? mx * (1.0f / 127.0f) : 0.0f;
  float acc[4] = {};
  float wsum = 0.0f;

  auto dec = [&](u32 d, float w) {
    acc[0] += w * (float)(d & 0xffu);           // v_cvt_f32_ubyte0
    acc[1] += w * (float)((d >> 8) & 0xffu);    // v_cvt_f32_ubyte1
    acc[2] += w * (float)((d >> 16) & 0xffu);   // v_cvt_f32_ubyte2
    acc[3] += w * (float)(d >> 24);             // v_cvt_f32_ubyte3
    wsum += w;
  };

  const int e1 = rowp[node + 1];
  int e = rowp[node];
  for (; e + B <= e1; e += B) {
    int s[B];
#pragma unroll
    for (int j = 0; j < B; ++j) s[j] = csr[e + j];
    float wv[B];
#pragma unroll
    for (int j = 0; j < B; ++j) wv[j] = dinv[s[j]];
    u32 v[B];
#pragma unroll
    for (int j = 0; j < B; ++j) v[j] = *(const u32*)(Hq + (size_t)s[j] * 256 + off);
#pragma unroll
    for (int j = 0; j < B; ++j) dec(v[j], wv[j]);
  }
  for (; e < e1; ++e) {
    int s = csr[e];
    dec(*(const u32*)(Hq + (size_t)s * 256 + off), dinv[s]);
  }
  const float wi = dinv[node];
  dec(*(const u32*)(Hq + (size_t)node * 256 + off), wi);

  float vals[4];
#pragma unroll
  for (int k = 0; k < 4; ++k) {
    float v = (acc[k] - 128.0f * wsum) * wi * sq;
    if (bias) v += bf2f(bias[off + k]);
    if (relu) v = fmaxf(v, 0.0f);
    vals[k] = v;
  }
  u32 d0 = (u32)f2bf(vals[0]) | ((u32)f2bf(vals[1]) << 16);
  u32 d1 = (u32)f2bf(vals[2]) | ((u32)f2bf(vals[3]) << 16);
  *(int2*)(G + (size_t)node * dst_stride + off) = make_int2((int)d0, (int)d1);
}

// ---------------- t4 bf16 -> biased uint8 quantize (global scale from maxbits) ----------------
__global__ void quant_kernel(const u16* __restrict__ t4, u8* __restrict__ t4q,
                             const u32* __restrict__ maxbits, int n4) {
  int i = blockIdx.x * 256 + threadIdx.x;
  if (i >= n4) return;
  float mx = __builtin_bit_cast(float, *maxbits);
  float inv = mx > 0.0f ? 127.0f / mx : 0.0f;
  int2 v = ((const int2*)t4)[i];
  float f0 = bf2f((u16)(v.x & 0xffff)), f1 = bf2f((u16)((u32)v.x >> 16));
  float f2 = bf2f((u16)(v.y & 0xffff)), f3 = bf2f((u16)((u32)v.y >> 16));
  int q0 = (int)rintf(f0 * inv), q1 = (int)rintf(f1 * inv);
  int q2 = (int)rintf(f2 * inv), q3 = (int)rintf(f3 * inv);
  q0 = min(127, max(-127, q0)) + 128; q1 = min(127, max(-127, q1)) + 128;
  q2 = min(127, max(-127, q2)) + 128; q3 = min(127, max(-127, q3)) + 128;
  ((u32*)t4q)[i] = (u32)q0 | ((u32)q1 << 8) | ((u32)q2 << 16) | ((u32)q3 << 24);
}

// ---------------- fast bf16 MFMA GEMM (m97 structure): C = A @ Bt^T ----------------
__global__ __launch_bounds__(256) void gemm_fast_kernel(
    const u16* __restrict__ A, int lda, const u16* __restrict__ Bt,
    u16* __restrict__ C, int ldc, const u16* __restrict__ bias,
    int M, int N, int K, int relu, int fp8out, u32* __restrict__ maxout) {
  __shared__ __align__(16) u16 sA[128 * 64];
  __shared__ __align__(16) u16 sB[128 * 64];
  const int tid = threadIdx.x;
  const int lane = tid & 63;
  const int wave = __builtin_amdgcn_readfirstlane(tid >> 6);
  const int m0 = blockIdx.y * 128, n0 = blockIdx.x * 128;
  const int wm = (wave & 1) * 64, wn = (wave >> 1) * 64;
  const int lr = lane & 15, lq = lane >> 4;
  const int lrow = lane >> 3;
  const int lcol = (lane & 7) * 8;
  f32x4 acc[4][4] = {};

  for (int kb = 0; kb < K; kb += 64) {
#pragma unroll
    for (int it = 0; it < 4; ++it) {
      const int rbase = (it * 4 + wave) * 8;
      int gm = m0 + rbase + lrow;
      if (gm >= M) gm = M - 1;
      __builtin_amdgcn_global_load_lds(GLB_PTR(A + (size_t)gm * lda + kb + lcol),
                                       LDS_PTR(sA + rbase * 64), 16, 0, 0);
      const int gn = n0 + rbase + lrow;
      __builtin_amdgcn_global_load_lds(GLB_PTR(Bt + (size_t)gn * K + kb + lcol),
                                       LDS_PTR(sB + rbase * 64), 16, 0, 0);
    }
    __syncthreads();
#pragma unroll
    for (int ks = 0; ks < 2; ++ks) {
      bf16x8 af[4], bfr[4];
#pragma unroll
      for (int i = 0; i < 4; ++i)
        af[i] = *(const bf16x8*)(sA + (wm + i * 16 + lr) * 64 + ks * 32 + lq * 8);
#pragma unroll
      for (int i = 0; i < 4; ++i)
        bfr[i] = *(const bf16x8*)(sB + (wn + i * 16 + lr) * 64 + ks * 32 + lq * 8);
#pragma unroll
      for (int im = 0; im < 4; ++im)
#pragma unroll
        for (int in = 0; in < 4; ++in)
          acc[im][in] = __builtin_amdgcn_mfma_f32_16x16x32_bf16(af[im], bfr[in], acc[im][in], 0, 0, 0);
    }
    __syncthreads();
  }
  u32 mymax = 0;
#pragma unroll
  for (int im = 0; im < 4; ++im) {
#pragma unroll
    for (int in = 0; in < 4; ++in) {
      int col = n0 + wn + in * 16 + lr;
      float bv = bias ? bf2f(bias[col]) : 0.0f;
#pragma unroll
      for (int r = 0; r < 4; ++r) {
        int row = m0 + wm + im * 16 + lq * 4 + r;
        if (row < M) {
          float v = acc[im][in][r] + bv;
          if (relu) v = fmaxf(v, 0.0f);
          if (maxout) {
            u32 ab = __builtin_bit_cast(u32, v) & 0x7fffffffu;
            mymax = mymax > ab ? mymax : ab;
          }
          if (fp8out) {
            int pk = __builtin_amdgcn_cvt_pk_fp8_f32(v, v, 0, false);
            ((u8*)C)[(size_t)row * ldc + col] = (u8)(pk & 0xff);
          } else {
            C[(size_t)row * ldc + col] = f2bf(v);
          }
        }
      }
    }
  }
  if (maxout) {
    u32* red = (u32*)sA;
    red[tid] = mymax;
    __syncthreads();
    for (int s = 128; s > 0; s >>= 1) {
      if (tid < s) red[tid] = red[tid] > red[tid + s] ? red[tid] : red[tid + s];
      __syncthreads();
    }
    if (tid == 0) atomicMax(maxout, red[0]);
  }
}

// ---------------- small/edge GEMM (padded-LDS, any K/N) ----------------
#define LP 72
__global__ __launch_bounds__(256) void gemm_small_kernel(
    const u16* __restrict__ A, int lda, const u16* __restrict__ Bt,
    u16* __restrict__ C, int ldc, const u16* __restrict__ bias,
    int M, int N, int K, int relu, int fp8out) {
  __shared__ __align__(16) u16 sA[128 * LP];
  __shared__ __align__(16) u16 sB[128 * LP];
  const int tid = threadIdx.x;
  const int lane = tid & 63, wave = tid >> 6;
  const int m0 = blockIdx.y * 128, n0 = blockIdx.x * 128;
  const int wm = (wave & 1) * 64, wn = (wave >> 1) * 64;
  const int lr = lane & 15;
  const int lq = lane >> 4;
  f32x4 acc[4][4] = {};

  for (int kb = 0; kb < K; kb += 64) {
#pragma unroll
    for (int it = 0; it < 4; ++it) {
      int linear = it * 2048 + tid * 8;
      int row = linear >> 6, kc = linear & 63;
      int gm = m0 + row, gk = kb + kc;
      int4 v = make_int4(0, 0, 0, 0);
      if (gm < M && gk < K) v = *(const int4*)(A + (size_t)gm * lda + gk);
      *(int4*)(sA + row * LP + kc) = v;
    }
#pragma unroll
    for (int it = 0; it < 4; ++it) {
      int linear = it * 2048 + tid * 8;
      int row = linear >> 6, kc = linear & 63;
      int gn = n0 + row, gk = kb + kc;
      int4 v = make_int4(0, 0, 0, 0);
      if (gn < N && gk < K) v = *(const int4*)(Bt + (size_t)gn * K + gk);
      *(int4*)(sB + row * LP + kc) = v;
    }
    __syncthreads();
#pragma unroll
    for (int ks = 0; ks < 2; ++ks) {
      bf16x8 af[4], bfr[4];
#pragma unroll
      for (int i = 0; i < 4; ++i)
        af[i] = *(const bf16x8*)(sA + (wm + i * 16 + lr) * LP + ks * 32 + lq * 8);
#pragma unroll
      for (int i = 0; i < 4; ++i)
        bfr[i] = *(const bf16x8*)(sB + (wn + i * 16 + lr) * LP + ks * 32 + lq * 8);
#pragma unroll
      for (int im = 0; im < 4; ++im)
#pragma unroll
        for (int in = 0; in < 4; ++in)
          acc[im][in] = __builtin_amdgcn_mfma_f32_16x16x32_bf16(af[im], bfr[in], acc[im][in], 0, 0, 0);
    }
    __syncthreads();
  }
#pragma unroll
  for (int im = 0; im < 4; ++im) {
#pragma unroll
    for (int in = 0; in < 4; ++in) {
      int col = n0 + wn + in * 16 + lr;
      if (col >= N) continue;
      float bv = bias ? bf2f(bias[col]) : 0.0f;
#pragma unroll
      for (int r = 0; r < 4; ++r) {
        int row = m0 + wm + im * 16 + lq * 4 + r;
        if (row < M) {
          float v = acc[im][in][r] + bv;
          if (relu) v = fmaxf(v, 0.0f);
          if (fp8out) {
            int pk = __builtin_amdgcn_cvt_pk_fp8_f32(v, v, 0, false);
            ((u8*)C)[(size_t)row * ldc + col] = (u8)(pk & 0xff);
          } else {
            C[(size_t)row * ldc + col] = f2bf(v);
          }
        }
      }
    }
  }
}

extern "C" void kernel_launch(void* const* d_in, const int* in_sizes, int n_in,
                              void* d_out, int out_size, void* d_ws, size_t ws_size,
                              hipStream_t stream) {
  const u16* x  = (const u16*)d_in[0];
  const int* ei = (const int*)d_in[1];

  const int Nn = in_sizes[0] / 32;   // 100000
  const int E  = in_sizes[1] / 2;    // 3200000
  const int CH = (Nn + 7) / 8;       // 12500
  const int NR = (Nn + CH - 1) / CH; // 8
  const int NB = (Nn + (1 << BSH) - 1) >> BSH;  // 196 buckets

  char* w = (char*)d_ws;
  size_t off = 0;
  auto alloc = [&](size_t bytes) -> void* {
    void* p = w + off;
    off = (off + bytes + 255) & ~(size_t)255;
    return p;
  };
  int*   flags  = (int*)alloc(256);
  int*   gcur   = (int*)alloc(1024);   // gcur, gbase, tmax contiguous: zeroed together
  int*   gbase  = (int*)alloc(1024);
  u32*   tmax   = (u32*)alloc(256);
  int*   rowp   = (int*)alloc((size_t)(Nn + 1) * 4);
  float* dinv   = (float*)alloc((size_t)Nn * 4);
  int*   csr    = (int*)alloc((size_t)E * 4);
  u16*   Wt1    = (u16*)alloc((size_t)32 * 256 * 2);
  u16*   Wt2    = (u16*)alloc((size_t)256 * 1024 * 2);
  u16*   Wt3    = (u16*)alloc((size_t)1024 * 1024 * 2);
  u16*   Wt4    = (u16*)alloc((size_t)1024 * 256 * 2);
  u16*   Wt5    = (u16*)alloc((size_t)256 * 6 * 2);
  u16*   bc1    = (u16*)alloc(256 * 2);
  u16*   bc2    = (u16*)alloc(1024 * 2);
  u16*   bc3    = (u16*)alloc(1024 * 2);
  u16*   bc4    = (u16*)alloc(256 * 2);
  u16*   bc5    = (u16*)alloc(6 * 2);
  size_t selems = (size_t)CH * 1024;
  u16*   S      = (u16*)alloc(selems * 2);             // 25.6 MB staging
  u16*   H      = (u16*)alloc((size_t)Nn * 1024 * 2);  // 204.8 MB main
  const size_t required = off;
  (void)n_in;

  if (ws_size < required) {
    if (ws_size >= 4096) {
      detect_kernel<<<3, 256, 0, stream>>>(ei, x, flags, gcur, 576);
      zero_out_kernel<<<(out_size + 255) / 256, 256, 0, stream>>>(d_out, out_size, flags);
    }
    return;
  }

  // H sub-regions (u16 element offsets):
  //   h2q : fp8  u16 [0, Nn*512)          (Nn x 1024 fp8; dead after last L3 chunk)
  //   t4q : u8   bytes [0, Nn*256)        (overlays dead h2q)
  //   g2/t4:     u16 [Nn*512, Nn*768)
  //   h1q : fp8  u16 [Nn*768, Nn*896)     (dead after L2 spmm)
  //   h3R/h4:    u16 [Nn*768, Nn*1024)
  u8*  h2q = (u8*)H;
  u8*  t4q = (u8*)H;
  u16* g2  = H + (size_t)Nn * 512;
  u16* t4  = H + (size_t)Nn * 512;
  u8*  h1q = (u8*)(H + (size_t)Nn * 768);
  u16* h3R = H + (size_t)Nn * 768;
  u16* h4  = H + (size_t)Nn * 768;

  int2* pairs = (int2*)H;  // CSR-build scratch, dead after build

  // ---- detection (+ zero gcur/gbase/tmax) + bucketed CSR build ----
  detect_kernel<<<3, 256, 0, stream>>>(ei, x, flags, gcur, 576);
  bin_kernel<<<1024, 256, 0, stream>>>(ei, gcur, pairs, E, Nn, flags, 1024);
  bucket_scan_kernel<<<1, 256, 0, stream>>>(gcur, gbase, NB);
  bucket_finalize_kernel<<<NB, 512, 0, stream>>>(pairs, gcur, gbase, rowp, dinv, csr, Nn);

  // ---- weights/biases -> bf16 [N,K], one fused launch ----
  {
    CvtArgs a;
    const int Ks[10] = {32, 1, 256, 1, 1024, 1, 1024, 1, 256, 1};
    const int Ns[10] = {256, 256, 1024, 1024, 1024, 1024, 256, 256, 6, 6};
    u16* ds[10] = {Wt1, bc1, Wt2, bc2, Wt3, bc3, Wt4, bc4, Wt5, bc5};
    int cum = 0;
    for (int t = 0; t < 10; ++t) {
      a.src[t] = d_in[2 + t];
      a.dst[t] = ds[t];
      a.K[t] = Ks[t];
      a.N[t] = Ns[t];
      a.start[t] = cum;
      cum += Ks[t] * Ns[t];
    }
    a.start[10] = cum;
    convert_all_kernel<<<(cum + 255) / 256, 256, 0, stream>>>(a, flags);
  }

  const int sg = (Nn + 3) / 4;
  const int mb = (Nn + 127) / 128;

  // L1: g1 = Â x -> S (Nn x 32; 2 nodes/wave); h1 = relu(g1@W1+b1) -> fp8 h1q (Nn x 256)
  spmm_narrow_kernel<2, 32, true, false><<<(Nn + 7) / 8, 256, 0, stream>>>(
      x, S, rowp, csr, dinv, nullptr, 0, Nn, 32, 32, flags);
  gemm_small_kernel<<<dim3(2, mb), 256, 0, stream>>>(S, 32, Wt1, (u16*)h1q, 256, bc1,
                                                     Nn, 256, 32, 1, 1);

  // L2: g2 = Â h1q (fp8, W=256) -> g2; h2 = relu(g2@W2+b2) -> fp8 h2q
  spmm_fp8_kernel<256><<<sg, 256, 0, stream>>>(h1q, g2, rowp, csr, dinv, 0, Nn, 256);
  gemm_fast_kernel<<<dim3(8, mb), 256, 0, stream>>>(g2, 256, Wt2, (u16*)h2q, 1024, bc2,
                                                    Nn, 1024, 256, 1, 1, nullptr);

  // L3+L4a per row-chunk; W4 epilogue tracks global max|t4| into tmax
  for (int R = 0; R < NR; ++R) {
    int n0 = R * CH;
    int n1 = n0 + CH < Nn ? n0 + CH : Nn;
    int MR = n1 - n0;
    int mbr = (MR + 127) / 128;
    spmm_fp8_kernel<1024><<<(MR + 3) / 4, 256, 0, stream>>>(h2q, S, rowp, csr, dinv, n0, n1, 1024);
    gemm_fast_kernel<<<dim3(8, mbr), 256, 0, stream>>>(S, 1024, Wt3, h3R, 1024, bc3,
                                                       MR, 1024, 1024, 1, 0, nullptr);
    gemm_fast_kernel<<<dim3(2, mbr), 256, 0, stream>>>(h3R, 1024, Wt4, t4 + (size_t)n0 * 256, 256,
                                                       nullptr, MR, 256, 1024, 0, 0, tmax);
  }

  // quantize t4 -> biased uint8 (global scale) into dead h2q space
  quant_kernel<<<(Nn * 64 + 255) / 256, 256, 0, stream>>>(t4, t4q, tmax, Nn * 64);

  // L4b: h4 = relu(Â t4q + b4) -> h4 (uint8 gather, W=256)
  spmm_u8_kernel<<<sg, 256, 0, stream>>>(t4q, h4, rowp, csr, dinv, tmax, bc4, 1, Nn, 256);

  // L5: t5 = h4@W5 -> S (Nn x 6); out = Â t5 + b5 (8 nodes/wave)
  gemm_small_kernel<<<dim3(1, mb), 256, 0, stream>>>(h4, 256, Wt5, S, 6, nullptr,
                                                     Nn, 6, 256, 0, 0);
  spmm_narrow_kernel<8, 6, false, true><<<(Nn + 31) / 32, 256, 0, stream>>>(
      S, d_out, rowp, csr, dinv, bc5, 0, Nn, 6, 6, flags);
}